// Round 5
// baseline (5605.214 us; speedup 1.0000x reference)
//
#include <hip/hip_runtime.h>

// B=2, streams=2, N=1024, D=256, H=4, DH=64, L=18
// Row layout: r = s*2048 + b*1024 + n  (M=4096 rows)
// bf16 MFMA 16x16x32: A-frag lane=A[m=lane&15][k=quad*8+j]; B-frag B[k=quad*8+j][n=lane&15]
// C/D: col=lane&15, row=quad*4+reg
// LDS XOR swizzle: 16B chunk c of row r stored at slot (c ^ (r&7)).
// BN stats PER STREAM via global fp32 atomics.
//
// NEW (R4->R5): the whole 18-layer loop is ONE persistent kernel (megaloop).
//   512 blocks x 256 thr, __launch_bounds__(256,2) + 68KB LDS => exactly 2 blocks/CU
//   => all 512 blocks co-resident => homemade device-wide barrier is safe.
//   71 grid barriers replace 71 kernel boundaries (~8us each measured).

typedef __attribute__((ext_vector_type(8))) short bf16x8;
typedef __attribute__((ext_vector_type(4))) short bf16x4;
typedef __attribute__((ext_vector_type(4))) float floatx4;

__device__ __forceinline__ short f2b(float f) {   // fp32 -> bf16 RNE
  unsigned u = __builtin_bit_cast(unsigned, f);
  unsigned r = (u + 0x7FFFu + ((u >> 16) & 1u)) >> 16;
  return (short)r;
}
__device__ __forceinline__ unsigned pack2(float a, float b) {
  return (unsigned)(unsigned short)f2b(a) | ((unsigned)(unsigned short)f2b(b) << 16);
}
__device__ __forceinline__ void split2(float a, float b, unsigned& h, unsigned& l) {
  unsigned short ha = (unsigned short)f2b(a), hb = (unsigned short)f2b(b);
  float fa = __builtin_bit_cast(float, (unsigned)ha << 16);
  float fb = __builtin_bit_cast(float, (unsigned)hb << 16);
  h = (unsigned)ha | ((unsigned)hb << 16);
  l = pack2(a - fa, b - fb);
}

__device__ __forceinline__ void gl2lds16(const void* g, void* l) {
  __builtin_amdgcn_global_load_lds(
      (const __attribute__((address_space(1))) unsigned*)g,
      (__attribute__((address_space(3))) unsigned*)l, 16, 0, 0);
}

__device__ __forceinline__ floatx4 mfma16_bf16(bf16x4 a, bf16x4 b, floatx4 c) {
#if __has_builtin(__builtin_amdgcn_mfma_f32_16x16x16_bf16)
  return __builtin_amdgcn_mfma_f32_16x16x16_bf16(a, b, c, 0, 0, 0);
#elif __has_builtin(__builtin_amdgcn_mfma_f32_16x16x16bf16_1k)
  return __builtin_amdgcn_mfma_f32_16x16x16bf16_1k(a, b, c, 0, 0, 0);
#else
  asm volatile("v_mfma_f32_16x16x16_bf16 %0, %1, %2, %0" : "+v"(c) : "v"(a), "v"(b));
  return c;
#endif
}

#define BARW   asm volatile("s_barrier" ::: "memory")
#define WAITV8 asm volatile("s_waitcnt vmcnt(8)" ::: "memory")
#define WAITV5 asm volatile("s_waitcnt vmcnt(5)" ::: "memory")
#define WAITV4 asm volatile("s_waitcnt vmcnt(4)" ::: "memory")
#define WAITV0 asm volatile("s_waitcnt vmcnt(0)" ::: "memory")
#define LGKM0  asm volatile("s_waitcnt lgkmcnt(0)" ::: "memory")

// device-wide sense-reversing barrier (all blocks co-resident by construction)
__device__ __forceinline__ void gridbar(unsigned* bar, int nb) {
  __syncthreads();
  if (threadIdx.x == 0) {
    unsigned g = __hip_atomic_load(&bar[1], __ATOMIC_RELAXED, __HIP_MEMORY_SCOPE_AGENT);
    __threadfence();   // release: writeback this XCD's L2
    unsigned v = __hip_atomic_fetch_add(&bar[0], 1u, __ATOMIC_ACQ_REL,
                                        __HIP_MEMORY_SCOPE_AGENT);
    if (v == (unsigned)(nb - 1)) {
      __hip_atomic_store(&bar[0], 0u, __ATOMIC_RELAXED, __HIP_MEMORY_SCOPE_AGENT);
      __hip_atomic_fetch_add(&bar[1], 1u, __ATOMIC_RELEASE, __HIP_MEMORY_SCOPE_AGENT);
    } else {
      while (__hip_atomic_load(&bar[1], __ATOMIC_ACQUIRE,
                               __HIP_MEMORY_SCOPE_AGENT) == g)
        __builtin_amdgcn_s_sleep(2);
    }
    __threadfence();   // acquire: invalidate stale lines
  }
  __syncthreads();
}

#define GEMM_IDS                                        \
  const int tid = threadIdx.x;                          \
  const int lane = tid & 63, w = tid >> 6;              \
  const int wy = w >> 1, wx = w & 1;                    \
  const int quad = lane >> 4, l16 = lane & 15;          \
  const int lr = lane >> 3;                             \
  const int lcs = (((lane & 7) ^ lr) & 7) * 8;          \
  const floatx4 z4 = {0.f, 0.f, 0.f, 0.f};

// swizzled MFMA K-step (BM=64, BN=128, wave-tile 32x64) -- wfuse only
__device__ __forceinline__ void mfma_step_sw(const short* As, const short* Bs,
                                             int wy, int wx, int quad, int l16,
                                             floatx4 acc[2][4]) {
#pragma unroll
  for (int kk = 0; kk < 2; ++kk) {
    const int sw = (((kk * 4 + quad) ^ (l16 & 7)) * 8);
    bf16x8 a0 = *(const bf16x8*)&As[(wy * 32 + l16) * 64 + sw];
    bf16x8 a1 = *(const bf16x8*)&As[(wy * 32 + 16 + l16) * 64 + sw];
    bf16x8 b[4];
#pragma unroll
    for (int ni = 0; ni < 4; ++ni)
      b[ni] = *(const bf16x8*)&Bs[(wx * 64 + ni * 16 + l16) * 64 + sw];
#pragma unroll
    for (int ni = 0; ni < 4; ++ni) {
      acc[0][ni] = __builtin_amdgcn_mfma_f32_16x16x32_bf16(a0, b[ni], acc[0][ni], 0, 0, 0);
      acc[1][ni] = __builtin_amdgcn_mfma_f32_16x16x32_bf16(a1, b[ni], acc[1][ni], 0, 0, 0);
    }
  }
}

// swizzled MFMA K-step (BM=32, BN=128, wave-tile 16x64)
__device__ __forceinline__ void mfma_step_sw32(const short* As, const short* Bs,
                                               int wy, int wx, int quad, int l16,
                                               floatx4 acc[4]) {
#pragma unroll
  for (int kk = 0; kk < 2; ++kk) {
    const int sw = (((kk * 4 + quad) ^ (l16 & 7)) * 8);
    bf16x8 a0 = *(const bf16x8*)&As[(wy * 16 + l16) * 64 + sw];
    bf16x8 b[4];
#pragma unroll
    for (int ni = 0; ni < 4; ++ni)
      b[ni] = *(const bf16x8*)&Bs[(wx * 64 + ni * 16 + l16) * 64 + sw];
#pragma unroll
    for (int ni = 0; ni < 4; ++ni)
      acc[ni] = __builtin_amdgcn_mfma_f32_16x16x32_bf16(a0, b[ni], acc[ni], 0, 0, 0);
  }
}

// swizzled MFMA K-step (BM=32, BN=64, wave-tile 16x32)
__device__ __forceinline__ void mfma_step_sw32x64(const short* As, const short* Bs,
                                                  int wy, int wx, int quad, int l16,
                                                  floatx4 acc[2]) {
#pragma unroll
  for (int kk = 0; kk < 2; ++kk) {
    const int sw = (((kk * 4 + quad) ^ (l16 & 7)) * 8);
    bf16x8 a0 = *(const bf16x8*)&As[(wy * 16 + l16) * 64 + sw];
    bf16x8 b[2];
#pragma unroll
    for (int ni = 0; ni < 2; ++ni)
      b[ni] = *(const bf16x8*)&Bs[(wx * 32 + ni * 16 + l16) * 64 + sw];
#pragma unroll
    for (int ni = 0; ni < 2; ++ni)
      acc[ni] = __builtin_amdgcn_mfma_f32_16x16x32_bf16(a0, b[ni], acc[ni], 0, 0, 0);
  }
}

// ---------- wfuse: F = ow(256x256) @ w1bot(256x512), F^T -> w1t[n][256+kp]
__global__ __launch_bounds__(256) void wfuse(
    const float* __restrict__ ow, const float* __restrict__ w1,
    short* __restrict__ wbuf) {
  __shared__ short As_h[64 * 64], As_l[64 * 64];
  __shared__ short Bs_h[128 * 64], Bs_l[128 * 64];
  const int blk = blockIdx.x;
  const int layer = blk >> 4, sub = blk & 15;
  const int kp0 = (sub & 3) * 64, n0 = (sub >> 2) * 128;
  const float* A = ow + (size_t)layer * 65536;
  const float* Bw = w1 + (size_t)layer * 262144 + 256 * 512;
  short* w1t = wbuf + (size_t)layer * 655360 + 262144;
  GEMM_IDS;
  (void)lr; (void)lcs;
  floatx4 acc[2][4] = {{z4, z4, z4, z4}, {z4, z4, z4, z4}};
  const int ar = tid >> 2, aq = tid & 3;
  const int bn = tid & 127, bkh = tid >> 7;

  for (int s = 0; s < 4; ++s) {
    const int k0 = s * 64;
    const float* Ar = &A[(size_t)(kp0 + ar) * 256 + k0 + aq * 16];
    float4 f0 = *(const float4*)&Ar[0];
    float4 f1 = *(const float4*)&Ar[4];
    float4 f2 = *(const float4*)&Ar[8];
    float4 f3 = *(const float4*)&Ar[12];
    float bv[32];
#pragma unroll
    for (int kk2 = 0; kk2 < 32; ++kk2)
      bv[kk2] = Bw[(size_t)(k0 + bkh * 32 + kk2) * 512 + n0 + bn];

    __syncthreads();
    {
      uint4 hi, lo;
      split2(f0.x, f0.y, hi.x, lo.x);
      split2(f0.z, f0.w, hi.y, lo.y);
      split2(f1.x, f1.y, hi.z, lo.z);
      split2(f1.z, f1.w, hi.w, lo.w);
      int sl = ((aq * 2) ^ (ar & 7)) * 8;
      *(uint4*)&As_h[ar * 64 + sl] = hi;
      *(uint4*)&As_l[ar * 64 + sl] = lo;
      split2(f2.x, f2.y, hi.x, lo.x);
      split2(f2.z, f2.w, hi.y, lo.y);
      split2(f3.x, f3.y, hi.z, lo.z);
      split2(f3.z, f3.w, hi.w, lo.w);
      sl = ((aq * 2 + 1) ^ (ar & 7)) * 8;
      *(uint4*)&As_h[ar * 64 + sl] = hi;
      *(uint4*)&As_l[ar * 64 + sl] = lo;
    }
#pragma unroll
    for (int cc = 0; cc < 4; ++cc) {
      uint4 hi, lo;
      split2(bv[cc * 8 + 0], bv[cc * 8 + 1], hi.x, lo.x);
      split2(bv[cc * 8 + 2], bv[cc * 8 + 3], hi.y, lo.y);
      split2(bv[cc * 8 + 4], bv[cc * 8 + 5], hi.z, lo.z);
      split2(bv[cc * 8 + 6], bv[cc * 8 + 7], hi.w, lo.w);
      int sl = ((bkh * 4 + cc) ^ (bn & 7)) * 8;
      *(uint4*)&Bs_h[bn * 64 + sl] = hi;
      *(uint4*)&Bs_l[bn * 64 + sl] = lo;
    }
    __syncthreads();
    mfma_step_sw(As_h, Bs_h, wy, wx, quad, l16, acc);
    mfma_step_sw(As_h, Bs_l, wy, wx, quad, l16, acc);
    mfma_step_sw(As_l, Bs_h, wy, wx, quad, l16, acc);
  }
#pragma unroll
  for (int mi = 0; mi < 2; ++mi)
#pragma unroll
    for (int ni = 0; ni < 4; ++ni) {
      int col = n0 + wx * 64 + ni * 16 + l16;
      int row0 = kp0 + wy * 32 + mi * 16 + quad * 4;
      uint2 uu;
      uu.x = pack2(acc[mi][ni][0], acc[mi][ni][1]);
      uu.y = pack2(acc[mi][ni][2], acc[mi][ni][3]);
      *(uint2*)&w1t[(size_t)col * 512 + 256 + row0] = uu;
    }
}

// ---------- prep kernel (+ zero of grid-barrier state)
__global__ __launch_bounds__(256) void wprep(
    const float* __restrict__ qw, const float* __restrict__ kw,
    const float* __restrict__ vw, const float* __restrict__ w1,
    const float* __restrict__ w2, const float* __restrict__ ob,
    const float* __restrict__ b1, short* __restrict__ wbuf,
    float* __restrict__ beff, const float* __restrict__ desc,
    float* __restrict__ xd, short* __restrict__ xb,
    float* __restrict__ psz, unsigned* __restrict__ bar) {
  __shared__ float SH[64 * 130];
  int blk = blockIdx.x;
  int t = threadIdx.x;
  if (blk < 1296) {
    int layer = blk / 72;
    int sub = blk % 72;
    const float* W; int Kd, Nd, k0, n0; size_t ooff;
    if (sub < 24) {
      int wsel = sub / 8; int tt = sub & 7;
      k0 = (tt >> 1) * 64; n0 = (tt & 1) * 128; Kd = 256; Nd = 256;
      W = (wsel == 0 ? qw : wsel == 1 ? kw : vw) + (size_t)layer * 65536;
      ooff = (size_t)wsel * 65536;
    } else if (sub < 56) {
      int tt = sub - 24; k0 = (tt >> 2) * 64; n0 = (tt & 3) * 128;
      Kd = 512; Nd = 512; W = w1 + (size_t)layer * 262144; ooff = 262144;
    } else {
      int tt = sub - 56; k0 = (tt >> 1) * 64; n0 = (tt & 1) * 128;
      Kd = 512; Nd = 256; W = w2 + (size_t)layer * 131072; ooff = 524288;
    }
    short* out = wbuf + (size_t)layer * 655360 + ooff;
    const int rr = t >> 4;
    const int c4 = (t & 15) * 4;
#pragma unroll
    for (int i = 0; i < 4; ++i)
#pragma unroll
      for (int hf = 0; hf < 2; ++hf) {
        float4 v = *(const float4*)&W[(size_t)(k0 + i * 16 + rr) * Nd + n0 + hf * 64 + c4];
        float* tp = &SH[(i * 16 + rr) * 130 + hf * 64 + c4];
        tp[0] = v.x; tp[1] = v.y; tp[2] = v.z; tp[3] = v.w;
      }
    __syncthreads();
    const int n = t >> 1;
    const int kh = (t & 1) * 32;
    float v[32];
#pragma unroll
    for (int kk = 0; kk < 32; ++kk)
      v[kk] = SH[(kh + kk) * 130 + n];
    unsigned u[16];
#pragma unroll
    for (int j2 = 0; j2 < 16; ++j2) u[j2] = pack2(v[2 * j2], v[2 * j2 + 1]);
    short* op = &out[(size_t)(n0 + n) * Kd + k0 + kh];
#pragma unroll
    for (int q4 = 0; q4 < 4; ++q4) {
      uint4 o; o.x = u[q4 * 4]; o.y = u[q4 * 4 + 1]; o.z = u[q4 * 4 + 2]; o.w = u[q4 * 4 + 3];
      *(uint4*)&op[q4 * 8] = o;
    }
  } else if (blk < 1440) {
    int bb = blk - 1296;
    int layer = bb >> 3;
    int n0 = (bb & 7) * 64;
    const float* obL = ob + (size_t)layer * 256;
    const float* w1L = w1 + (size_t)layer * 262144 + 256 * 512;
    int n = n0 + (t & 63);
    int part = t >> 6;
    float s = 0.f;
    for (int i = part * 64; i < part * 64 + 64; ++i)
      s += obL[i] * w1L[(size_t)i * 512 + n];
    SH[part * 64 + (t & 63)] = s;
    __syncthreads();
    if (t < 64) {
      float tot = SH[t] + SH[64 + t] + SH[128 + t] + SH[192 + t] +
                  b1[(size_t)layer * 512 + n0 + t];
      beff[(size_t)layer * 512 + n0 + t] = tot;
    }
  } else if (blk < 2464) {
    int idx = (blk - 1440) * 256 + t;
    int fi = idx << 2;
    int hi = (fi >> 19) & 1;
    int lo = (fi >> 18) & 1;
    int sj = (fi & ~(3 << 18)) | (lo << 19) | (hi << 18);
    float4 v = *(const float4*)&desc[sj];
    *(float4*)&xd[fi] = v;
    uint2 uu; uu.x = pack2(v.x, v.y); uu.y = pack2(v.z, v.w);
    *(uint2*)&xb[fi] = uu;
  } else {
    int idx = (blk - 2464) * 1024 + t * 4;
    float4 zz = {0.f, 0.f, 0.f, 0.f};
    *(float4*)&psz[idx] = zz;
    if (blk == 2464 && t == 0) { bar[0] = 0u; bar[1] = 0u; }
  }
}

// ---------- THE persistent kernel: 18 layers, 4 phases each, grid barriers between.
// 512 blocks x 256 thr, 2 blocks/CU (forced by launch_bounds + 68KB LDS).
__global__ __launch_bounds__(256, 2) void megaloop(
    short* __restrict__ xb, float* __restrict__ xd, float* __restrict__ hbuf,
    short* __restrict__ qb16, short* __restrict__ kb16, short* __restrict__ vTb,
    short* __restrict__ attnb, float* __restrict__ psum, float* __restrict__ psq,
    const float* __restrict__ beff, const short* __restrict__ wbuf,
    const int* __restrict__ mask,
    const float* __restrict__ qb, const float* __restrict__ kb,
    const float* __restrict__ vb, const float* __restrict__ b2,
    const float* __restrict__ bn_g, const float* __restrict__ bn_b,
    float* __restrict__ out, unsigned* __restrict__ bar) {
  __shared__ __align__(16) char SMB[69632];
  const int nb = (int)gridDim.x;
  const int bid = (int)blockIdx.x;
  GEMM_IDS;

  for (int i = 0; i < 18; ++i) {
    const int cross = i & 1;
    const short* wb = wbuf + (size_t)i * 655360;
    const float* qbL = qb + (size_t)i * 256;
    const float* kbL = kb + (size_t)i * 256;
    const float* vbL = vb + (size_t)i * 256;
    const float* beffL = beff + (size_t)i * 512;
    float* psumL = psum + (size_t)i * 1024;
    float* psqL  = psq  + (size_t)i * 1024;

    // ================= phase 1: fused QKV GEMM (768 tiles) =================
    {
      short* As = (short*)SMB;             // [2][2048]
      short* Bs = (short*)(SMB + 8192);    // [2][8192]
      for (int tile = bid; tile < 768; tile += nb) {
        __syncthreads();                   // LDS handoff (2 tiles/block)
        const int rb = (tile & 127) * 32;
        const int cbi = tile >> 7;         // 0..5
        const int cb = cbi * 128;
        const int seg = cb >> 8;
        const int cbl = cb & 255;
        int arb = rb;
        if (seg) arb = (rb & 2047) | ((((rb >> 11) ^ cross) & 1) << 11);
        const short* A = xb + (size_t)arb * 256;
        const short* Wt = wb + (size_t)seg * 65536 + (size_t)cbl * 256;
        const float* bias = (seg == 0 ? qbL : seg == 1 ? kbL : vbL) + cbl;
        floatx4 acc[4] = {z4, z4, z4, z4};

#define QKV_STAGE(s, buf)                                                          \
  {                                                                                \
    int k0 = (s) * 64;                                                             \
    gl2lds16(&A[(size_t)(w * 8 + lr) * 256 + k0 + lcs], &As[(buf) * 2048 + (w * 8) * 64]); \
    _Pragma("unroll") for (int ii = 0; ii < 4; ++ii)                               \
      gl2lds16(&Wt[(size_t)(ii * 32 + w * 8 + lr) * 256 + k0 + lcs],               \
               &Bs[(buf) * 8192 + (ii * 32 + w * 8) * 64]);                        \
  }
        QKV_STAGE(0, 0);
        QKV_STAGE(1, 1);
        for (int s = 0; s < 4; ++s) {
          int buf = s & 1;
          if (s < 3) { WAITV5; } else { WAITV0; }
          BARW;
          mfma_step_sw32(&As[buf * 2048], &Bs[buf * 8192], wy, wx, quad, l16, acc);
          BARW;
          if (s < 2) QKV_STAGE(s + 2, buf);
        }
#undef QKV_STAGE

        if (seg < 2) {
          short* C = (seg == 0 ? qb16 : kb16) + (size_t)rb * 256 + cbl;
#pragma unroll
          for (int ni = 0; ni < 4; ++ni) {
            int col = wx * 64 + ni * 16 + l16;
            float bc = bias[col];
#pragma unroll
            for (int reg = 0; reg < 4; ++reg) {
              int row = wy * 16 + quad * 4 + reg;
              C[(size_t)row * 256 + col] = f2b(acc[ni][reg] + bc);
            }
          }
        } else {
          short* T = (short*)SMB + 4096 + w * 1536;   // wave-local scratch in Bs buf0
          const int sb = rb >> 10;
          const int hh = (cbl >> 6) + wx;
          const int z = sb * 4 + hh;
#pragma unroll
          for (int ni = 0; ni < 4; ++ni) {
            int col = wx * 64 + ni * 16 + l16;
            float bc = bias[col];
#pragma unroll
            for (int reg = 0; reg < 4; ++reg)
              T[(ni * 16 + l16) * 24 + quad * 4 + reg] = f2b(acc[ni][reg] + bc);
          }
          short* dst = &vTb[((size_t)z * 64 + lane) * 1024 + (rb & 1023) + wy * 16];
          *(uint4*)&dst[0] = *(const uint4*)&T[lane * 24 + 0];
          *(uint4*)&dst[8] = *(const uint4*)&T[lane * 24 + 8];
        }
      }
      gridbar(bar, nb);
    }

    // ================= phase 2: flash attention (512 tiles) =================
    {
      short (*Ks)[2][4096] = (short(*)[2][4096])SMB;             // 32KB
      short (*Vs)[2][4096] = (short(*)[2][4096])(SMB + 32768);   // 32KB
      float* Msk = (float*)(SMB + 65536);                        // 4KB
      for (int tile = bid; tile < 512; tile += nb) {
        __syncthreads();
        const int qt = tile & 31;
        const int z = tile >> 5;
        const int wv = w & 1, wq = w >> 1;
        const int sb = z >> 2, h = z & 3;
        const int s = sb >> 1, b = sb & 1;
        const int rowbase = sb * 1024;
        const int* mp = mask + (b * 2 + (s ^ cross)) * 1024;

        const int qrow = qt * 32 + wq * 16 + l16;
        bf16x8 qf[2];
#pragma unroll
        for (int kk = 0; kk < 2; ++kk)
          qf[kk] = *(const bf16x8*)&qb16[(size_t)(rowbase + qrow) * 256 + h * 64 +
                                         kk * 32 + quad * 8];
        {  // mask -> LDS bias
          int4 mv = *(const int4*)&mp[tid * 4];
          Msk[tid * 4 + 0] = (mv.x == 0) ? -1.0e9f : 0.f;
          Msk[tid * 4 + 1] = (mv.y == 0) ? -1.0e9f : 0.f;
          Msk[tid * 4 + 2] = (mv.z == 0) ? -1.0e9f : 0.f;
          Msk[tid * 4 + 3] = (mv.w == 0) ? -1.0e9f : 0.f;
        }
        floatx4 o4[4] = {z4, z4, z4, z4};
        float mrun = -1e30f, lsum = 0.f;

#define ATT_STAGE(t, buf)                                                               \
  {                                                                                     \
    int key0s = wv * 512 + (t) * 64;                                                    \
    _Pragma("unroll") for (int j = 0; j < 4; ++j) {                                     \
      gl2lds16(&kb16[(size_t)(rowbase + key0s + j * 16 + wq * 8 + lr) * 256 + h * 64 + lcs], \
               &Ks[buf][wv][(j * 16 + wq * 8) * 64]);                                   \
      gl2lds16(&vTb[((size_t)z * 64 + j * 16 + wq * 8 + lr) * 1024 + key0s + lcs],      \
               &Vs[buf][wv][(j * 16 + wq * 8) * 64]);                                   \
    }                                                                                   \
  }
        ATT_STAGE(0, 0);
        __syncthreads();
        for (int t = 0; t < 8; ++t) {
          int buf = t & 1;
          if (t < 7) { ATT_STAGE(t + 1, buf ^ 1); WAITV8; } else { WAITV0; }
          BARW;
          const int key0 = wv * 512 + t * 64;

          floatx4 sA[4] = {z4, z4, z4, z4};
          __builtin_amdgcn_s_setprio(1);
#pragma unroll
          for (int kk = 0; kk < 2; ++kk) {
            const int sw = (((kk * 4 + quad) ^ (l16 & 7)) * 8);
#pragma unroll
            for (int mt = 0; mt < 4; ++mt) {
              bf16x8 kf = *(const bf16x8*)&Ks[buf][wv][(mt * 16 + l16) * 64 + sw];
              sA[mt] = __builtin_amdgcn_mfma_f32_16x16x32_bf16(kf, qf[kk], sA[mt], 0, 0, 0);
            }
          }
          __builtin_amdgcn_s_setprio(0);
          float scv[4][4];
          float tmax = -1e30f;
#pragma unroll
          for (int mt = 0; mt < 4; ++mt) {
            float4 mk = *(const float4*)&Msk[key0 + mt * 16 + quad * 4];
            scv[mt][0] = sA[mt][0] * 0.125f + mk.x;
            scv[mt][1] = sA[mt][1] * 0.125f + mk.y;
            scv[mt][2] = sA[mt][2] * 0.125f + mk.z;
            scv[mt][3] = sA[mt][3] * 0.125f + mk.w;
#pragma unroll
            for (int reg = 0; reg < 4; ++reg) tmax = fmaxf(tmax, scv[mt][reg]);
          }
          tmax = fmaxf(tmax, __shfl_xor(tmax, 16));
          tmax = fmaxf(tmax, __shfl_xor(tmax, 32));
          float mnew = fmaxf(mrun, tmax);
          float corr = __expf(mrun - mnew);
          mrun = mnew;
          lsum *= corr;
#pragma unroll
          for (int dt = 0; dt < 4; ++dt)
#pragma unroll
            for (int reg = 0; reg < 4; ++reg) o4[dt][reg] *= corr;

          bf16x4 pb[4];
#pragma unroll
          for (int mt = 0; mt < 4; ++mt) {
            float e0 = __expf(scv[mt][0] - mnew);
            float e1 = __expf(scv[mt][1] - mnew);
            float e2 = __expf(scv[mt][2] - mnew);
            float e3 = __expf(scv[mt][3] - mnew);
            lsum += (e0 + e1) + (e2 + e3);
            union { bf16x4 v; uint2 u; } pu;
            pu.u.x = pack2(e0, e1); pu.u.y = pack2(e2, e3);
            pb[mt] = pu.v;
          }
          __builtin_amdgcn_s_setprio(1);
#pragma unroll
          for (int mt = 0; mt < 4; ++mt) {
            const int c2 = mt * 2 + (quad >> 1);
            const int sub = (quad & 1) * 4;
#pragma unroll
            for (int dt = 0; dt < 4; ++dt) {
              bf16x4 vf = *(const bf16x4*)&Vs[buf][wv][(dt * 16 + l16) * 64 +
                                                       ((c2 ^ (l16 & 7)) * 8) + sub];
              o4[dt] = mfma16_bf16(vf, pb[mt], o4[dt]);
            }
          }
          __builtin_amdgcn_s_setprio(0);
          LGKM0;
          BARW;
        }
#undef ATT_STAGE
        lsum += __shfl_xor(lsum, 16);
        lsum += __shfl_xor(lsum, 32);

        float* MG = (float*)SMB;
        const int mo = (wq * 64 + lane) * 18;
        if (wv == 1) {
          MG[mo] = mrun;
          MG[mo + 1] = lsum;
#pragma unroll
          for (int dt = 0; dt < 4; ++dt)
#pragma unroll
            for (int reg = 0; reg < 4; ++reg) MG[mo + 2 + dt * 4 + reg] = o4[dt][reg];
        }
        __syncthreads();
        if (wv == 0) {
          float m2 = MG[mo], l2 = MG[mo + 1];
          float mm = fmaxf(mrun, m2);
          float ca = __expf(mrun - mm), cb2 = __expf(m2 - mm);
          float inv = 1.f / (ca * lsum + cb2 * l2);
          short* op = &attnb[(size_t)(rowbase + qrow) * 256 + h * 64 + quad * 4];
#pragma unroll
          for (int dt = 0; dt < 4; ++dt) {
            float v0 = (ca * o4[dt][0] + cb2 * MG[mo + 2 + dt * 4 + 0]) * inv;
            float v1 = (ca * o4[dt][1] + cb2 * MG[mo + 2 + dt * 4 + 1]) * inv;
            float v2 = (ca * o4[dt][2] + cb2 * MG[mo + 2 + dt * 4 + 2]) * inv;
            float v3 = (ca * o4[dt][3] + cb2 * MG[mo + 2 + dt * 4 + 3]) * inv;
            uint2 uu;
            uu.x = pack2(v0, v1);
            uu.y = pack2(v2, v3);
            *(uint2*)&op[dt * 16] = uu;
          }
        }
      }
      gridbar(bar, nb);
    }

    // ================= phase 3: W1 GEMM + BN partials (512 tiles) =================
    {
      short* As = (short*)SMB;
      short* Bs = (short*)(SMB + 8192);
      float (*Ps)[2][128] = (float(*)[2][128])(SMB + 40960);
      for (int tile = bid; tile < 512; tile += nb) {
        __syncthreads();
        const int rb = (tile & 127) * 32;
        const int cb = (tile >> 7) * 128;
        const int str = rb >> 11;
        floatx4 acc[4] = {z4, z4, z4, z4};

#define W1_STAGE(s, buf)                                                            \
  {                                                                                 \
    int k0 = (s) * 64;                                                              \
    const short* Ap = ((s) < 4 ? xb : attnb) + (size_t)rb * 256;                    \
    int kbk = k0 & 255;                                                             \
    gl2lds16(&Ap[(size_t)(w * 8 + lr) * 256 + kbk + lcs], &As[(buf) * 2048 + (w * 8) * 64]); \
    _Pragma("unroll") for (int ii = 0; ii < 4; ++ii)                                \
      gl2lds16(&wb[262144 + (size_t)(cb + ii * 32 + w * 8 + lr) * 512 + k0 + lcs],  \
               &Bs[(buf) * 8192 + (ii * 32 + w * 8) * 64]);                         \
  }
        W1_STAGE(0, 0);
        W1_STAGE(1, 1);
        for (int s = 0; s < 8; ++s) {
          int buf = s & 1;
          if (s < 7) { WAITV5; } else { WAITV0; }
          BARW;
          mfma_step_sw32(&As[buf * 2048], &Bs[buf * 8192], wy, wx, quad, l16, acc);
          BARW;
          if (s < 6) W1_STAGE(s + 2, buf);
        }
#undef W1_STAGE
        float colsum[4], colsq[4];
#pragma unroll
        for (int ni = 0; ni < 4; ++ni) { colsum[ni] = 0.f; colsq[ni] = 0.f; }
#pragma unroll
        for (int ni = 0; ni < 4; ++ni) {
          int col = wx * 64 + ni * 16 + l16;
          float bc = beffL[cb + col];
#pragma unroll
          for (int reg = 0; reg < 4; ++reg) {
            int row = rb + wy * 16 + quad * 4 + reg;
            float val = acc[ni][reg] + bc;
            hbuf[(size_t)row * 512 + cb + col] = val;
            colsum[ni] += val; colsq[ni] += val * val;
          }
        }
#pragma unroll
        for (int ni = 0; ni < 4; ++ni)
#pragma unroll
          for (int d = 16; d < 64; d <<= 1) {
            colsum[ni] += __shfl_xor(colsum[ni], d);
            colsq[ni]  += __shfl_xor(colsq[ni], d);
          }
        if (quad == 0) {
#pragma unroll
          for (int ni = 0; ni < 4; ++ni) {
            Ps[wy][0][wx * 64 + ni * 16 + l16] = colsum[ni];
            Ps[wy][1][wx * 64 + ni * 16 + l16] = colsq[ni];
          }
        }
        __syncthreads();
        if (tid < 128) {
          atomicAdd(&psumL[str * 512 + cb + tid], Ps[0][0][tid] + Ps[1][0][tid]);
          atomicAdd(&psqL [str * 512 + cb + tid], Ps[0][1][tid] + Ps[1][1][tid]);
        }
      }
      gridbar(bar, nb);
    }

    // ================= phase 4: W2 GEMM + BN/ReLU + residual (512 tiles) ============
    {
      short* As = (short*)SMB;                       // [2][2048]
      short* Bs = (short*)(SMB + 8192);              // [2][4096]
      float* s_scale = (float*)(SMB + 24576);
      float* s_shift = (float*)(SMB + 26624);
      float* outp = (i == 17) ? out : nullptr;
      const float* gL = bn_g + (size_t)i * 512;
      const float* beL = bn_b + (size_t)i * 512;
      const float* b2L = b2 + (size_t)i * 256;
      for (int tile = bid; tile < 512; tile += nb) {
        __syncthreads();
        const int rb = (tile & 127) * 32;
        const int cb = (tile >> 7) * 64;
        const int str = rb >> 11;
        floatx4 acc[2] = {z4, z4};
#pragma unroll
        for (int cc = 0; cc < 2; ++cc) {
          int c = tid + cc * 256;
          float sum = psumL[str * 512 + c];
          float sq  = psqL [str * 512 + c];
          float mean = sum * (1.f / 2048.f);
          float var = sq * (1.f / 2048.f) - mean * mean;
          float rstd = rsqrtf(var + 1e-5f);
          float gs = gL[c] * rstd;
          s_scale[c] = gs;
          s_shift[c] = beL[c] - mean * gs;
        }
        __syncthreads();

        const int p = tid & 7, ar = tid >> 3;
        float4 ra0, ra1;

#define W2_A_LOAD(s)                                                               \
  {                                                                                \
    int k0 = (s) * 64;                                                             \
    int cs = k0 + ((p ^ (ar & 7)) * 8);                                            \
    ra0 = *(const float4*)&hbuf[(size_t)(rb + ar) * 512 + cs];                     \
    ra1 = *(const float4*)&hbuf[(size_t)(rb + ar) * 512 + cs + 4];                 \
  }
#define W2_A_WRITE(s, buf)                                                         \
  {                                                                                \
    int k0 = (s) * 64;                                                             \
    int cs = k0 + ((p ^ (ar & 7)) * 8);                                            \
    float4 sc0 = *(const float4*)&s_scale[cs];                                     \
    float4 sc1 = *(const float4*)&s_scale[cs + 4];                                 \
    float4 sh0 = *(const float4*)&s_shift[cs];                                     \
    float4 sh1 = *(const float4*)&s_shift[cs + 4];                                 \
    uint4 pk;                                                                      \
    pk.x = pack2(fmaxf(ra0.x * sc0.x + sh0.x, 0.f), fmaxf(ra0.y * sc0.y + sh0.y, 0.f)); \
    pk.y = pack2(fmaxf(ra0.z * sc0.z + sh0.z, 0.f), fmaxf(ra0.w * sc0.w + sh0.w, 0.f)); \
    pk.z = pack2(fmaxf(ra1.x * sc1.x + sh1.x, 0.f), fmaxf(ra1.y * sc1.y + sh1.y, 0.f)); \
    pk.w = pack2(fmaxf(ra1.z * sc1.z + sh1.z, 0.f), fmaxf(ra1.w * sc1.w + sh1.w, 0.f)); \
    *(uint4*)&As[(buf) * 2048 + ar * 64 + p * 8] = pk;                             \
  }
#define W2_STAGE_B(s, buf)                                                         \
  {                                                                                \
    int k0 = (s) * 64;                                                             \
    _Pragma("unroll") for (int ii = 0; ii < 2; ++ii)                               \
      gl2lds16(&wb[524288 + (size_t)(cb + ii * 32 + w * 8 + lr) * 512 + k0 + lcs], \
               &Bs[(buf) * 4096 + (ii * 32 + w * 8) * 64]);                        \
  }
        W2_A_LOAD(0);
        W2_STAGE_B(0, 0);
        W2_A_WRITE(0, 0);
        LGKM0;
        for (int s = 0; s < 8; ++s) {
          int buf = s & 1;
          if (s < 7) { W2_A_LOAD(s + 1); W2_STAGE_B(s + 1, buf ^ 1); WAITV4; } else { WAITV0; }
          BARW;
          mfma_step_sw32x64(&As[buf * 2048], &Bs[buf * 4096], wy, wx, quad, l16, acc);
          if (s < 7) W2_A_WRITE(s + 1, buf ^ 1);
          LGKM0;
          BARW;
        }
#undef W2_A_LOAD
#undef W2_A_WRITE
#undef W2_STAGE_B
#pragma unroll
        for (int ni = 0; ni < 2; ++ni) {
          int col = cb + wx * 32 + ni * 16 + l16;
          float bc = b2L[col];
#pragma unroll
          for (int reg = 0; reg < 4; ++reg) {
            int row = rb + wy * 16 + quad * 4 + reg;
            float r = xd[(size_t)row * 256 + col] + acc[ni][reg] + bc;
            xd[(size_t)row * 256 + col] = r;
            xb[(size_t)row * 256 + col] = f2b(r);
            if (outp) {
              int ss = row >> 11, bb = (row >> 10) & 1, n = row & 1023;
              outp[(size_t)((bb * 2 + ss) * 1024 + n) * 256 + col] = r;
            }
          }
        }
      }
      if (i < 17) gridbar(bar, nb);
    }
  }
}

extern "C" void kernel_launch(void* const* d_in, const int* in_sizes, int n_in,
                              void* d_out, int out_size, void* d_ws, size_t ws_size,
                              hipStream_t stream) {
  (void)in_sizes; (void)n_in; (void)out_size; (void)ws_size;
  const float* desc = (const float*)d_in[0];
  const int*   mask = (const int*)d_in[1];
  const float* qw = (const float*)d_in[2];
  const float* qb = (const float*)d_in[3];
  const float* kw = (const float*)d_in[4];
  const float* kb = (const float*)d_in[5];
  const float* vw = (const float*)d_in[6];
  const float* vb = (const float*)d_in[7];
  const float* ow = (const float*)d_in[8];
  const float* ob = (const float*)d_in[9];
  const float* w1 = (const float*)d_in[10];
  const float* b1 = (const float*)d_in[11];
  const float* bn_g = (const float*)d_in[12];
  const float* bn_b = (const float*)d_in[13];
  const float* w2 = (const float*)d_in[14];
  const float* b2 = (const float*)d_in[15];
  float* out = (float*)d_out;

  char* base = (char*)d_ws;
  float* xd    = (float*)(base);                  // [0,4) MB
  float* hbuf  = (float*)(base + (4u << 20));     // [4,12) MB
  short* xb    = (short*)(base + (12u << 20));
  short* qb16  = (short*)(base + (14u << 20));
  short* kb16  = (short*)(base + (16u << 20));
  short* vTb   = (short*)(base + (18u << 20));
  short* attnb = (short*)(base + (20u << 20));
  float* psum  = (float*)(base + (22u << 20));    // [18][2][512]
  float* psq   = psum + 18 * 1024;                // [18][2][512]
  float* beff  = psq + 18 * 1024;                 // 18*512 fp32
  unsigned* bar = (unsigned*)(beff + 18 * 512);   // grid barrier state (2 words)
  short* wbuf  = (short*)(base + (24u << 20));    // 18*655360 shorts = 23.6 MB

  wprep<<<2500, 256, 0, stream>>>(qw, kw, vw, w1, w2, ob, b1,
                                  wbuf, beff, desc, xd, xb, psum, bar);
  wfuse<<<288, 256, 0, stream>>>(ow, w1, wbuf);
  megaloop<<<512, 256, 0, stream>>>(xb, xd, hbuf, qb16, kb16, vTb, attnb,
                                    psum, psq, beff, wbuf, mask,
                                    qb, kb, vb, b2, bn_g, bn_b, out, bar);
}

// Round 6
// 946.284 us; speedup vs baseline: 5.9234x; 5.9234x over previous
//
#include <hip/hip_runtime.h>

// B=2, streams=2, N=1024, D=256, H=4, DH=64, L=18
// Row layout: r = s*2048 + b*1024 + n  (M=4096 rows)
// bf16 MFMA 16x16x32: A-frag lane=A[m=lane&15][k=quad*8+j]; B-frag B[k=quad*8+j][n=lane&15]
// C/D: col=lane&15, row=quad*4+reg
// LDS XOR swizzle: 16B chunk c of row r stored at slot (c ^ (r&7)).
// BN stats PER STREAM (2048 rows each), accumulated via global fp32 atomics.
// All hot K-loops: issue-stage-first + counted vmcnt + raw s_barrier (never drain mid-loop)
// + s_setprio(1) around MFMA clusters (T5; pays on phase-split counted-vmcnt loops).
// NOTE (R5 lesson): persistent kernel + homemade grid barrier = ~69us/barrier on CDNA4
// (acquire-spin thrashes all XCD L2s); kernel boundaries (~8us) are the cheap sync.

typedef __attribute__((ext_vector_type(8))) short bf16x8;
typedef __attribute__((ext_vector_type(4))) short bf16x4;
typedef __attribute__((ext_vector_type(4))) float floatx4;

__device__ __forceinline__ short f2b(float f) {   // fp32 -> bf16 RNE
  unsigned u = __builtin_bit_cast(unsigned, f);
  unsigned r = (u + 0x7FFFu + ((u >> 16) & 1u)) >> 16;
  return (short)r;
}
__device__ __forceinline__ unsigned pack2(float a, float b) {
  return (unsigned)(unsigned short)f2b(a) | ((unsigned)(unsigned short)f2b(b) << 16);
}
// split a,b into bf16-hi pair (packed) and fp32-residual bf16 pair (packed)
__device__ __forceinline__ void split2(float a, float b, unsigned& h, unsigned& l) {
  unsigned short ha = (unsigned short)f2b(a), hb = (unsigned short)f2b(b);
  float fa = __builtin_bit_cast(float, (unsigned)ha << 16);
  float fb = __builtin_bit_cast(float, (unsigned)hb << 16);
  h = (unsigned)ha | ((unsigned)hb << 16);
  l = pack2(a - fa, b - fb);
}

__device__ __forceinline__ void gl2lds16(const void* g, void* l) {
  __builtin_amdgcn_global_load_lds(
      (const __attribute__((address_space(1))) unsigned*)g,
      (__attribute__((address_space(3))) unsigned*)l, 16, 0, 0);
}

__device__ __forceinline__ floatx4 mfma16_bf16(bf16x4 a, bf16x4 b, floatx4 c) {
#if __has_builtin(__builtin_amdgcn_mfma_f32_16x16x16_bf16)
  return __builtin_amdgcn_mfma_f32_16x16x16_bf16(a, b, c, 0, 0, 0);
#elif __has_builtin(__builtin_amdgcn_mfma_f32_16x16x16bf16_1k)
  return __builtin_amdgcn_mfma_f32_16x16x16bf16_1k(a, b, c, 0, 0, 0);
#else
  asm volatile("v_mfma_f32_16x16x16_bf16 %0, %1, %2, %0" : "+v"(c) : "v"(a), "v"(b));
  return c;
#endif
}

#define BARW   asm volatile("s_barrier" ::: "memory")
#define WAITV8 asm volatile("s_waitcnt vmcnt(8)" ::: "memory")
#define WAITV5 asm volatile("s_waitcnt vmcnt(5)" ::: "memory")
#define WAITV4 asm volatile("s_waitcnt vmcnt(4)" ::: "memory")
#define WAITV0 asm volatile("s_waitcnt vmcnt(0)" ::: "memory")
#define LGKM0  asm volatile("s_waitcnt lgkmcnt(0)" ::: "memory")
#define PRIO1  __builtin_amdgcn_s_setprio(1)
#define PRIO0  __builtin_amdgcn_s_setprio(0)

#define GEMM_IDS                                        \
  const int tid = threadIdx.x;                          \
  const int lane = tid & 63, w = tid >> 6;              \
  const int wy = w >> 1, wx = w & 1;                    \
  const int quad = lane >> 4, l16 = lane & 15;          \
  const int lr = lane >> 3;                             \
  const int lcs = (((lane & 7) ^ lr) & 7) * 8;          \
  const floatx4 z4 = {0.f, 0.f, 0.f, 0.f};

// swizzled MFMA K-step (BM=64, BN=128, wave-tile 32x64) -- used by wfuse only
__device__ __forceinline__ void mfma_step_sw(const short* As, const short* Bs,
                                             int wy, int wx, int quad, int l16,
                                             floatx4 acc[2][4]) {
#pragma unroll
  for (int kk = 0; kk < 2; ++kk) {
    const int sw = (((kk * 4 + quad) ^ (l16 & 7)) * 8);
    bf16x8 a0 = *(const bf16x8*)&As[(wy * 32 + l16) * 64 + sw];
    bf16x8 a1 = *(const bf16x8*)&As[(wy * 32 + 16 + l16) * 64 + sw];
    bf16x8 b[4];
#pragma unroll
    for (int ni = 0; ni < 4; ++ni)
      b[ni] = *(const bf16x8*)&Bs[(wx * 64 + ni * 16 + l16) * 64 + sw];
#pragma unroll
    for (int ni = 0; ni < 4; ++ni) {
      acc[0][ni] = __builtin_amdgcn_mfma_f32_16x16x32_bf16(a0, b[ni], acc[0][ni], 0, 0, 0);
      acc[1][ni] = __builtin_amdgcn_mfma_f32_16x16x32_bf16(a1, b[ni], acc[1][ni], 0, 0, 0);
    }
  }
}

// swizzled MFMA K-step (BM=32, BN=128, wave-tile 16x64)
__device__ __forceinline__ void mfma_step_sw32(const short* As, const short* Bs,
                                               int wy, int wx, int quad, int l16,
                                               floatx4 acc[4]) {
#pragma unroll
  for (int kk = 0; kk < 2; ++kk) {
    const int sw = (((kk * 4 + quad) ^ (l16 & 7)) * 8);
    bf16x8 a0 = *(const bf16x8*)&As[(wy * 16 + l16) * 64 + sw];
    bf16x8 b[4];
#pragma unroll
    for (int ni = 0; ni < 4; ++ni)
      b[ni] = *(const bf16x8*)&Bs[(wx * 64 + ni * 16 + l16) * 64 + sw];
#pragma unroll
    for (int ni = 0; ni < 4; ++ni)
      acc[ni] = __builtin_amdgcn_mfma_f32_16x16x32_bf16(a0, b[ni], acc[ni], 0, 0, 0);
  }
}

// swizzled MFMA K-step (BM=32, BN=64, wave-tile 16x32)
__device__ __forceinline__ void mfma_step_sw32x64(const short* As, const short* Bs,
                                                  int wy, int wx, int quad, int l16,
                                                  floatx4 acc[2]) {
#pragma unroll
  for (int kk = 0; kk < 2; ++kk) {
    const int sw = (((kk * 4 + quad) ^ (l16 & 7)) * 8);
    bf16x8 a0 = *(const bf16x8*)&As[(wy * 16 + l16) * 64 + sw];
    bf16x8 b[2];
#pragma unroll
    for (int ni = 0; ni < 2; ++ni)
      b[ni] = *(const bf16x8*)&Bs[(wx * 32 + ni * 16 + l16) * 64 + sw];
#pragma unroll
    for (int ni = 0; ni < 2; ++ni)
      acc[ni] = __builtin_amdgcn_mfma_f32_16x16x32_bf16(a0, b[ni], acc[ni], 0, 0, 0);
  }
}

// ---------- wfuse: F = ow(256x256) @ w1bot(256x512), F^T -> w1t[n][256+kp]
// MFMA with bf16 hi/lo 3-term split. 64x128 tiles, grid 18*16=288.
__global__ __launch_bounds__(256) void wfuse(
    const float* __restrict__ ow, const float* __restrict__ w1,
    short* __restrict__ wbuf) {
  __shared__ short As_h[64 * 64], As_l[64 * 64];
  __shared__ short Bs_h[128 * 64], Bs_l[128 * 64];
  const int blk = blockIdx.x;
  const int layer = blk >> 4, sub = blk & 15;
  const int kp0 = (sub & 3) * 64, n0 = (sub >> 2) * 128;
  const float* A = ow + (size_t)layer * 65536;                 // [kp][i], 256-stride
  const float* Bw = w1 + (size_t)layer * 262144 + 256 * 512;   // [i][n], 512-stride
  short* w1t = wbuf + (size_t)layer * 655360 + 262144;
  GEMM_IDS;
  (void)lr; (void)lcs;
  floatx4 acc[2][4] = {{z4, z4, z4, z4}, {z4, z4, z4, z4}};
  const int ar = tid >> 2, aq = tid & 3;
  const int bn = tid & 127, bkh = tid >> 7;

  for (int s = 0; s < 4; ++s) {
    const int k0 = s * 64;
    const float* Ar = &A[(size_t)(kp0 + ar) * 256 + k0 + aq * 16];
    float4 f0 = *(const float4*)&Ar[0];
    float4 f1 = *(const float4*)&Ar[4];
    float4 f2 = *(const float4*)&Ar[8];
    float4 f3 = *(const float4*)&Ar[12];
    float bv[32];
#pragma unroll
    for (int kk2 = 0; kk2 < 32; ++kk2)
      bv[kk2] = Bw[(size_t)(k0 + bkh * 32 + kk2) * 512 + n0 + bn];

    __syncthreads();
    {
      uint4 hi, lo;
      split2(f0.x, f0.y, hi.x, lo.x);
      split2(f0.z, f0.w, hi.y, lo.y);
      split2(f1.x, f1.y, hi.z, lo.z);
      split2(f1.z, f1.w, hi.w, lo.w);
      int sl = ((aq * 2) ^ (ar & 7)) * 8;
      *(uint4*)&As_h[ar * 64 + sl] = hi;
      *(uint4*)&As_l[ar * 64 + sl] = lo;
      split2(f2.x, f2.y, hi.x, lo.x);
      split2(f2.z, f2.w, hi.y, lo.y);
      split2(f3.x, f3.y, hi.z, lo.z);
      split2(f3.z, f3.w, hi.w, lo.w);
      sl = ((aq * 2 + 1) ^ (ar & 7)) * 8;
      *(uint4*)&As_h[ar * 64 + sl] = hi;
      *(uint4*)&As_l[ar * 64 + sl] = lo;
    }
#pragma unroll
    for (int cc = 0; cc < 4; ++cc) {
      uint4 hi, lo;
      split2(bv[cc * 8 + 0], bv[cc * 8 + 1], hi.x, lo.x);
      split2(bv[cc * 8 + 2], bv[cc * 8 + 3], hi.y, lo.y);
      split2(bv[cc * 8 + 4], bv[cc * 8 + 5], hi.z, lo.z);
      split2(bv[cc * 8 + 6], bv[cc * 8 + 7], hi.w, lo.w);
      int sl = ((bkh * 4 + cc) ^ (bn & 7)) * 8;
      *(uint4*)&Bs_h[bn * 64 + sl] = hi;
      *(uint4*)&Bs_l[bn * 64 + sl] = lo;
    }
    __syncthreads();
    mfma_step_sw(As_h, Bs_h, wy, wx, quad, l16, acc);
    mfma_step_sw(As_h, Bs_l, wy, wx, quad, l16, acc);
    mfma_step_sw(As_l, Bs_h, wy, wx, quad, l16, acc);
  }
#pragma unroll
  for (int mi = 0; mi < 2; ++mi)
#pragma unroll
    for (int ni = 0; ni < 4; ++ni) {
      int col = n0 + wx * 64 + ni * 16 + l16;             // n
      int row0 = kp0 + wy * 32 + mi * 16 + quad * 4;      // kp base
      uint2 uu;
      uu.x = pack2(acc[mi][ni][0], acc[mi][ni][1]);
      uu.y = pack2(acc[mi][ni][2], acc[mi][ni][3]);
      *(uint2*)&w1t[(size_t)col * 512 + 256 + row0] = uu;
    }
}

// ---------- prep kernel:
// blocks [0,1296): wconv transpose+convert, 64k x 128n tiles (8 loads in flight)
// blocks [1296,1440): bfuse
// blocks [1440,2464): input swap-copy
// blocks [2464,2500): zero psum/psq
__global__ __launch_bounds__(256) void wprep(
    const float* __restrict__ qw, const float* __restrict__ kw,
    const float* __restrict__ vw, const float* __restrict__ w1,
    const float* __restrict__ w2, const float* __restrict__ ob,
    const float* __restrict__ b1, short* __restrict__ wbuf,
    float* __restrict__ beff, const float* __restrict__ desc,
    float* __restrict__ xd, short* __restrict__ xb,
    float* __restrict__ psz) {
  __shared__ float SH[64 * 130];
  int blk = blockIdx.x;
  int t = threadIdx.x;
  if (blk < 1296) {
    int layer = blk / 72;
    int sub = blk % 72;
    const float* W; int Kd, Nd, k0, n0; size_t ooff;
    if (sub < 24) {
      int wsel = sub / 8; int tt = sub & 7;
      k0 = (tt >> 1) * 64; n0 = (tt & 1) * 128; Kd = 256; Nd = 256;
      W = (wsel == 0 ? qw : wsel == 1 ? kw : vw) + (size_t)layer * 65536;
      ooff = (size_t)wsel * 65536;
    } else if (sub < 56) {
      int tt = sub - 24; k0 = (tt >> 2) * 64; n0 = (tt & 3) * 128;   // top half of w1
      Kd = 512; Nd = 512; W = w1 + (size_t)layer * 262144; ooff = 262144;
    } else {
      int tt = sub - 56; k0 = (tt >> 1) * 64; n0 = (tt & 1) * 128;
      Kd = 512; Nd = 256; W = w2 + (size_t)layer * 131072; ooff = 524288;
    }
    short* out = wbuf + (size_t)layer * 655360 + ooff;
    const int rr = t >> 4;
    const int c4 = (t & 15) * 4;
#pragma unroll
    for (int i = 0; i < 4; ++i)
#pragma unroll
      for (int hf = 0; hf < 2; ++hf) {
        float4 v = *(const float4*)&W[(size_t)(k0 + i * 16 + rr) * Nd + n0 + hf * 64 + c4];
        float* tp = &SH[(i * 16 + rr) * 130 + hf * 64 + c4];
        tp[0] = v.x; tp[1] = v.y; tp[2] = v.z; tp[3] = v.w;
      }
    __syncthreads();
    const int n = t >> 1;
    const int kh = (t & 1) * 32;
    float v[32];
#pragma unroll
    for (int kk = 0; kk < 32; ++kk)
      v[kk] = SH[(kh + kk) * 130 + n];
    unsigned u[16];
#pragma unroll
    for (int j2 = 0; j2 < 16; ++j2) u[j2] = pack2(v[2 * j2], v[2 * j2 + 1]);
    short* op = &out[(size_t)(n0 + n) * Kd + k0 + kh];
#pragma unroll
    for (int q4 = 0; q4 < 4; ++q4) {
      uint4 o; o.x = u[q4 * 4]; o.y = u[q4 * 4 + 1]; o.z = u[q4 * 4 + 2]; o.w = u[q4 * 4 + 3];
      *(uint4*)&op[q4 * 8] = o;
    }
  } else if (blk < 1440) {
    int bb = blk - 1296;
    int layer = bb >> 3;
    int n0 = (bb & 7) * 64;
    const float* obL = ob + (size_t)layer * 256;
    const float* w1L = w1 + (size_t)layer * 262144 + 256 * 512;
    int n = n0 + (t & 63);
    int part = t >> 6;
    float s = 0.f;
    for (int i = part * 64; i < part * 64 + 64; ++i)
      s += obL[i] * w1L[(size_t)i * 512 + n];
    SH[part * 64 + (t & 63)] = s;
    __syncthreads();
    if (t < 64) {
      float tot = SH[t] + SH[64 + t] + SH[128 + t] + SH[192 + t] +
                  b1[(size_t)layer * 512 + n0 + t];
      beff[(size_t)layer * 512 + n0 + t] = tot;
    }
  } else if (blk < 2464) {
    int idx = (blk - 1440) * 256 + t;
    int fi = idx << 2;
    int hi = (fi >> 19) & 1;
    int lo = (fi >> 18) & 1;
    int sj = (fi & ~(3 << 18)) | (lo << 19) | (hi << 18);
    float4 v = *(const float4*)&desc[sj];
    *(float4*)&xd[fi] = v;
    uint2 uu; uu.x = pack2(v.x, v.y); uu.y = pack2(v.z, v.w);
    *(uint2*)&xb[fi] = uu;
  } else {
    int idx = (blk - 2464) * 1024 + t * 4;
    float4 zz = {0.f, 0.f, 0.f, 0.f};
    *(float4*)&psz[idx] = zz;
  }
}

// ---------- fused QKV GEMM: BM=32, grid (128, 6); v-seg writes V^T
// counted-vmcnt 2-deep pipeline (5 gl2lds16 per stage per wave) + setprio MFMA.
__global__ __launch_bounds__(256) void gemm_qkv(
    const short* __restrict__ xb, const short* __restrict__ wbufL,
    const float* __restrict__ qb_, const float* __restrict__ kb_,
    const float* __restrict__ vb_,
    short* __restrict__ q, short* __restrict__ kout, short* __restrict__ vT,
    int cross) {
  __shared__ short SM[2 * 2048 + 2 * 8192];
  short* As = SM;            // [2][2048]
  short* Bs = SM + 4096;     // [2][8192]
  const int rb = blockIdx.x * 32;
  const int cb = blockIdx.y * 128;
  const int seg = cb >> 8;
  const int cbl = cb & 255;
  int arb = rb;
  if (seg) arb = (rb & 2047) | ((((rb >> 11) ^ cross) & 1) << 11);
  const short* A = xb + (size_t)arb * 256;
  const short* Wt = wbufL + (size_t)seg * 65536 + (size_t)cbl * 256;
  const float* bias = (seg == 0 ? qb_ : seg == 1 ? kb_ : vb_) + cbl;
  GEMM_IDS;
  floatx4 acc[4] = {z4, z4, z4, z4};

#define QKV_STAGE(s, buf)                                                          \
  {                                                                                \
    int k0 = (s) * 64;                                                             \
    gl2lds16(&A[(size_t)(w * 8 + lr) * 256 + k0 + lcs], &As[(buf) * 2048 + (w * 8) * 64]); \
    _Pragma("unroll") for (int i = 0; i < 4; ++i)                                  \
      gl2lds16(&Wt[(size_t)(i * 32 + w * 8 + lr) * 256 + k0 + lcs],                \
               &Bs[(buf) * 8192 + (i * 32 + w * 8) * 64]);                         \
  }

  QKV_STAGE(0, 0);
  QKV_STAGE(1, 1);
  for (int s = 0; s < 4; ++s) {
    int buf = s & 1;
    if (s < 3) { WAITV5; } else { WAITV0; }
    BARW;
    PRIO1;
    mfma_step_sw32(&As[buf * 2048], &Bs[buf * 8192], wy, wx, quad, l16, acc);
    PRIO0;
    BARW;
    if (s < 2) QKV_STAGE(s + 2, buf);
  }

  if (seg < 2) {
    short* C = (seg == 0 ? q : kout) + (size_t)rb * 256 + cbl;
#pragma unroll
    for (int ni = 0; ni < 4; ++ni) {
      int col = wx * 64 + ni * 16 + l16;
      float bc = bias[col];
#pragma unroll
      for (int reg = 0; reg < 4; ++reg) {
        int row = wy * 16 + quad * 4 + reg;
        C[(size_t)row * 256 + col] = f2b(acc[ni][reg] + bc);
      }
    }
  } else {
    // T in Bs buf0 region [4096,12288) -- final mfma step read buf1 only.
    short* T = SM + 4096 + w * 1536;     // 64 dims x 24 (pad), wave-local
    const int sb = rb >> 10;
    const int hh = (cbl >> 6) + wx;
    const int z = sb * 4 + hh;
#pragma unroll
    for (int ni = 0; ni < 4; ++ni) {
      int col = wx * 64 + ni * 16 + l16;
      float bc = bias[col];
#pragma unroll
      for (int reg = 0; reg < 4; ++reg)
        T[(ni * 16 + l16) * 24 + quad * 4 + reg] = f2b(acc[ni][reg] + bc);
    }
    short* dst = &vT[((size_t)z * 64 + lane) * 1024 + (rb & 1023) + wy * 16];
    *(uint4*)&dst[0] = *(const uint4*)&T[lane * 24 + 0];
    *(uint4*)&dst[8] = *(const uint4*)&T[lane * 24 + 8];
  }
#undef QKV_STAGE
}

// ---------- flash attention, S^T/O^T form, KV-split.
// grid (32,16), 256 thr = 4 waves: (wq = q sub-tile 0/1) x (wv = KV half 0/1).
// Mask pre-staged to LDS (no vmem in compute). Issue-first + vmcnt(8) pipeline.
__global__ __launch_bounds__(256) void attn_mfma(
    const short* __restrict__ q, const short* __restrict__ k,
    const short* __restrict__ vT, const int* __restrict__ mask,
    short* __restrict__ attnb, int cross) {
  __shared__ short Ks[2][2][4096];   // [buf][wv][64 keys x 64 dims]
  __shared__ short Vs[2][2][4096];   // [buf][wv][64 dims x 64 keys]
  __shared__ float Msk[1024];
  const int tid = threadIdx.x;
  const int lane = tid & 63, w = tid >> 6;
  const int wv = w & 1, wq = w >> 1;
  const int quad = lane >> 4, l16 = lane & 15;
  const int lr = lane >> 3;
  const int lcs = (((lane & 7) ^ lr) & 7) * 8;
  const int qt = blockIdx.x;
  const int z = blockIdx.y;
  const int sb = z >> 2, h = z & 3;
  const int s = sb >> 1, b = sb & 1;
  const int rowbase = sb * 1024;
  const int* mp = mask + (b * 2 + (s ^ cross)) * 1024;

  const int qrow = qt * 32 + wq * 16 + l16;      // this lane's query
  bf16x8 qf[2];
#pragma unroll
  for (int kk = 0; kk < 2; ++kk)
    qf[kk] = *(const bf16x8*)&q[(size_t)(rowbase + qrow) * 256 + h * 64 + kk * 32 + quad * 8];

  {  // mask -> LDS bias, once
    int4 mv = *(const int4*)&mp[tid * 4];
    Msk[tid * 4 + 0] = (mv.x == 0) ? -1.0e9f : 0.f;
    Msk[tid * 4 + 1] = (mv.y == 0) ? -1.0e9f : 0.f;
    Msk[tid * 4 + 2] = (mv.z == 0) ? -1.0e9f : 0.f;
    Msk[tid * 4 + 3] = (mv.w == 0) ? -1.0e9f : 0.f;
  }

  const floatx4 z4 = {0.f, 0.f, 0.f, 0.f};
  floatx4 o4[4] = {z4, z4, z4, z4};
  float mrun = -1e30f, lsum = 0.f;

#define ATT_STAGE(t, buf)                                                               \
  {                                                                                     \
    int key0s = wv * 512 + (t) * 64;                                                    \
    _Pragma("unroll") for (int j = 0; j < 4; ++j) {                                     \
      gl2lds16(&k[(size_t)(rowbase + key0s + j * 16 + wq * 8 + lr) * 256 + h * 64 + lcs], \
               &Ks[buf][wv][(j * 16 + wq * 8) * 64]);                                   \
      gl2lds16(&vT[((size_t)z * 64 + j * 16 + wq * 8 + lr) * 1024 + key0s + lcs],       \
               &Vs[buf][wv][(j * 16 + wq * 8) * 64]);                                   \
    }                                                                                   \
  }

  ATT_STAGE(0, 0);
  __syncthreads();     // drains stage(0) + publishes Msk
  for (int t = 0; t < 8; ++t) {
    int buf = t & 1;
    if (t < 7) { ATT_STAGE(t + 1, buf ^ 1); WAITV8; } else { WAITV0; }
    BARW;
    const int key0 = wv * 512 + t * 64;

    // S^T tiles: A=K-frag (m=key), B=Q-frag (n=query)
    floatx4 sA[4] = {z4, z4, z4, z4};
    PRIO1;
#pragma unroll
    for (int kk = 0; kk < 2; ++kk) {
      const int sw = (((kk * 4 + quad) ^ (l16 & 7)) * 8);
#pragma unroll
      for (int mt = 0; mt < 4; ++mt) {
        bf16x8 kf = *(const bf16x8*)&Ks[buf][wv][(mt * 16 + l16) * 64 + sw];
        sA[mt] = __builtin_amdgcn_mfma_f32_16x16x32_bf16(kf, qf[kk], sA[mt], 0, 0, 0);
      }
    }
    PRIO0;
    float scv[4][4];
    float tmax = -1e30f;
#pragma unroll
    for (int mt = 0; mt < 4; ++mt) {
      float4 mk = *(const float4*)&Msk[key0 + mt * 16 + quad * 4];
      scv[mt][0] = sA[mt][0] * 0.125f + mk.x;
      scv[mt][1] = sA[mt][1] * 0.125f + mk.y;
      scv[mt][2] = sA[mt][2] * 0.125f + mk.z;
      scv[mt][3] = sA[mt][3] * 0.125f + mk.w;
#pragma unroll
      for (int reg = 0; reg < 4; ++reg) tmax = fmaxf(tmax, scv[mt][reg]);
    }
    tmax = fmaxf(tmax, __shfl_xor(tmax, 16));
    tmax = fmaxf(tmax, __shfl_xor(tmax, 32));
    float mnew = fmaxf(mrun, tmax);
    float corr = __expf(mrun - mnew);
    mrun = mnew;
    lsum *= corr;
#pragma unroll
    for (int dt = 0; dt < 4; ++dt)
#pragma unroll
      for (int reg = 0; reg < 4; ++reg) o4[dt][reg] *= corr;

    bf16x4 pb[4];
#pragma unroll
    for (int mt = 0; mt < 4; ++mt) {
      float e0 = __expf(scv[mt][0] - mnew);
      float e1 = __expf(scv[mt][1] - mnew);
      float e2 = __expf(scv[mt][2] - mnew);
      float e3 = __expf(scv[mt][3] - mnew);
      lsum += (e0 + e1) + (e2 + e3);
      union { bf16x4 v; uint2 u; } pu;
      pu.u.x = pack2(e0, e1); pu.u.y = pack2(e2, e3);
      pb[mt] = pu.v;
    }
    // O^T += V^T @ P^T  (P^T straight from registers)
    PRIO1;
#pragma unroll
    for (int mt = 0; mt < 4; ++mt) {
      const int c2 = mt * 2 + (quad >> 1);
      const int sub = (quad & 1) * 4;
#pragma unroll
      for (int dt = 0; dt < 4; ++dt) {
        bf16x4 vf = *(const bf16x4*)&Vs[buf][wv][(dt * 16 + l16) * 64 +
                                                 ((c2 ^ (l16 & 7)) * 8) + sub];
        o4[dt] = mfma16_bf16(vf, pb[mt], o4[dt]);
      }
    }
    PRIO0;
    LGKM0;
    BARW;
  }
  lsum += __shfl_xor(lsum, 16);
  lsum += __shfl_xor(lsum, 32);

  // merge the two KV halves via LDS (reuse Ks as fp32 scratch)
  float* MG = (float*)&Ks[0][0][0];
  const int mo = (wq * 64 + lane) * 18;
  if (wv == 1) {
    MG[mo] = mrun;
    MG[mo + 1] = lsum;
#pragma unroll
    for (int dt = 0; dt < 4; ++dt)
#pragma unroll
      for (int reg = 0; reg < 4; ++reg) MG[mo + 2 + dt * 4 + reg] = o4[dt][reg];
  }
  __syncthreads();
  if (wv == 0) {
    float m2 = MG[mo], l2 = MG[mo + 1];
    float mm = fmaxf(mrun, m2);
    float ca = __expf(mrun - mm), cb2 = __expf(m2 - mm);
    float inv = 1.f / (ca * lsum + cb2 * l2);
    short* op = &attnb[(size_t)(rowbase + qrow) * 256 + h * 64 + quad * 4];
#pragma unroll
    for (int dt = 0; dt < 4; ++dt) {
      float v0 = (ca * o4[dt][0] + cb2 * MG[mo + 2 + dt * 4 + 0]) * inv;
      float v1 = (ca * o4[dt][1] + cb2 * MG[mo + 2 + dt * 4 + 1]) * inv;
      float v2 = (ca * o4[dt][2] + cb2 * MG[mo + 2 + dt * 4 + 2]) * inv;
      float v3 = (ca * o4[dt][3] + cb2 * MG[mo + 2 + dt * 4 + 3]) * inv;
      uint2 uu;
      uu.x = pack2(v0, v1);
      uu.y = pack2(v2, v3);
      *(uint2*)&op[dt * 16] = uu;
    }
  }
#undef ATT_STAGE
}

// ---------- W1 GEMM (concat [x | attn]) + BN partial atomics. BM=32, grid (128,4)
// counted-vmcnt 2-deep pipeline (5 gl2lds16 per stage per wave) + setprio MFMA.
__global__ __launch_bounds__(256) void gemm_w1(
    const short* __restrict__ xb, const short* __restrict__ attnb,
    const short* __restrict__ w1t, const float* __restrict__ beff,
    float* __restrict__ hbuf, float* __restrict__ psumL, float* __restrict__ psqL) {
  __shared__ short SM[2 * 2048 + 2 * 8192];
  __shared__ float Ps[2][2][128];
  short* As = SM;
  short* Bs = SM + 4096;
  const int rb = blockIdx.x * 32, cb = blockIdx.y * 128;
  const int str = rb >> 11;      // stream for BN stats
  GEMM_IDS;
  floatx4 acc[4] = {z4, z4, z4, z4};

#define W1_STAGE(s, buf)                                                            \
  {                                                                                 \
    int k0 = (s) * 64;                                                              \
    const short* Ap = ((s) < 4 ? xb : attnb) + (size_t)rb * 256;                    \
    int kb = k0 & 255;                                                              \
    gl2lds16(&Ap[(size_t)(w * 8 + lr) * 256 + kb + lcs], &As[(buf) * 2048 + (w * 8) * 64]); \
    _Pragma("unroll") for (int i = 0; i < 4; ++i)                                   \
      gl2lds16(&w1t[(size_t)(cb + i * 32 + w * 8 + lr) * 512 + k0 + lcs],           \
               &Bs[(buf) * 8192 + (i * 32 + w * 8) * 64]);                          \
  }

  W1_STAGE(0, 0);
  W1_STAGE(1, 1);
  for (int s = 0; s < 8; ++s) {
    int buf = s & 1;
    if (s < 7) { WAITV5; } else { WAITV0; }
    BARW;
    PRIO1;
    mfma_step_sw32(&As[buf * 2048], &Bs[buf * 8192], wy, wx, quad, l16, acc);
    PRIO0;
    BARW;
    if (s < 6) W1_STAGE(s + 2, buf);
  }
  float colsum[4], colsq[4];
#pragma unroll
  for (int ni = 0; ni < 4; ++ni) { colsum[ni] = 0.f; colsq[ni] = 0.f; }
#pragma unroll
  for (int ni = 0; ni < 4; ++ni) {
    int col = wx * 64 + ni * 16 + l16;
    float bc = beff[cb + col];
#pragma unroll
    for (int reg = 0; reg < 4; ++reg) {
      int row = rb + wy * 16 + quad * 4 + reg;
      float val = acc[ni][reg] + bc;
      hbuf[(size_t)row * 512 + cb + col] = val;
      colsum[ni] += val; colsq[ni] += val * val;
    }
  }
#pragma unroll
  for (int ni = 0; ni < 4; ++ni)
#pragma unroll
    for (int d = 16; d < 64; d <<= 1) {
      colsum[ni] += __shfl_xor(colsum[ni], d);
      colsq[ni]  += __shfl_xor(colsq[ni], d);
    }
  if (quad == 0) {
#pragma unroll
    for (int ni = 0; ni < 4; ++ni) {
      Ps[wy][0][wx * 64 + ni * 16 + l16] = colsum[ni];
      Ps[wy][1][wx * 64 + ni * 16 + l16] = colsq[ni];
    }
  }
  __syncthreads();
  if (tid < 128) {
    atomicAdd(&psumL[str * 512 + cb + tid], Ps[0][0][tid] + Ps[1][0][tid]);
    atomicAdd(&psqL [str * 512 + cb + tid], Ps[0][1][tid] + Ps[1][1][tid]);
  }
#undef W1_STAGE
}

// ---------- W2: cheap BN finalize + T14 split A-staging (issue-early/write-late)
// + counted-vmcnt raw-barrier loop + setprio MFMA. BM=32, BN=64, grid (128,4).
__global__ __launch_bounds__(256) void gemm_w2(
    const float* __restrict__ hbuf, const short* __restrict__ w2t,
    const float* __restrict__ b2_, const float* __restrict__ psumL,
    const float* __restrict__ psqL, const float* __restrict__ g,
    const float* __restrict__ be, float* __restrict__ xd, short* __restrict__ xb,
    float* __restrict__ outp) {
  __shared__ short SM[2 * 2048 + 2 * 4096];
  __shared__ float s_scale[512], s_shift[512];
  short* As = SM;            // [2][2048]
  short* Bs = SM + 4096;     // [2][4096]
  const int rb = blockIdx.x * 32, cb = blockIdx.y * 64;
  const int str = rb >> 11;
  GEMM_IDS;
  floatx4 acc[2] = {z4, z4};
#pragma unroll
  for (int cc = 0; cc < 2; ++cc) {
    int c = tid + cc * 256;
    float sum = psumL[str * 512 + c];
    float sq  = psqL [str * 512 + c];
    float mean = sum * (1.f / 2048.f);
    float var = sq * (1.f / 2048.f) - mean * mean;
    float rstd = rsqrtf(var + 1e-5f);
    float gs = g[c] * rstd;
    s_scale[c] = gs;
    s_shift[c] = be[c] - mean * gs;
  }
  __syncthreads();

  const int p = tid & 7, ar = tid >> 3;   // ar 0..31
  float4 ra0, ra1;

#define W2_A_LOAD(s)                                                               \
  {                                                                                \
    int k0 = (s) * 64;                                                             \
    int cs = k0 + ((p ^ (ar & 7)) * 8);                                            \
    ra0 = *(const float4*)&hbuf[(size_t)(rb + ar) * 512 + cs];                     \
    ra1 = *(const float4*)&hbuf[(size_t)(rb + ar) * 512 + cs + 4];                 \
  }
#define W2_A_WRITE(s, buf)                                                         \
  {                                                                                \
    int k0 = (s) * 64;                                                             \
    int cs = k0 + ((p ^ (ar & 7)) * 8);                                            \
    float4 sc0 = *(const float4*)&s_scale[cs];                                     \
    float4 sc1 = *(const float4*)&s_scale[cs + 4];                                 \
    float4 sh0 = *(const float4*)&s_shift[cs];                                     \
    float4 sh1 = *(const float4*)&s_shift[cs + 4];                                 \
    uint4 pk;                                                                      \
    pk.x = pack2(fmaxf(ra0.x * sc0.x + sh0.x, 0.f), fmaxf(ra0.y * sc0.y + sh0.y, 0.f)); \
    pk.y = pack2(fmaxf(ra0.z * sc0.z + sh0.z, 0.f), fmaxf(ra0.w * sc0.w + sh0.w, 0.f)); \
    pk.z = pack2(fmaxf(ra1.x * sc1.x + sh1.x, 0.f), fmaxf(ra1.y * sc1.y + sh1.y, 0.f)); \
    pk.w = pack2(fmaxf(ra1.z * sc1.z + sh1.z, 0.f), fmaxf(ra1.w * sc1.w + sh1.w, 0.f)); \
    *(uint4*)&As[(buf) * 2048 + ar * 64 + p * 8] = pk;                             \
  }
#define W2_STAGE_B(s, buf)                                                         \
  {                                                                                \
    int k0 = (s) * 64;                                                             \
    _Pragma("unroll") for (int i = 0; i < 2; ++i)                                  \
      gl2lds16(&w2t[(size_t)(cb + i * 32 + w * 8 + lr) * 512 + k0 + lcs],          \
               &Bs[(buf) * 4096 + (i * 32 + w * 8) * 64]);                         \
  }

  W2_A_LOAD(0);
  W2_STAGE_B(0, 0);
  W2_A_WRITE(0, 0);
  LGKM0;
  for (int s = 0; s < 8; ++s) {
    int buf = s & 1;
    if (s < 7) { W2_A_LOAD(s + 1); W2_STAGE_B(s + 1, buf ^ 1); WAITV4; } else { WAITV0; }
    BARW;
    PRIO1;
    mfma_step_sw32x64(&As[buf * 2048], &Bs[buf * 4096], wy, wx, quad, l16, acc);
    PRIO0;
    if (s < 7) W2_A_WRITE(s + 1, buf ^ 1);
    LGKM0;
    BARW;
  }
#pragma unroll
  for (int ni = 0; ni < 2; ++ni) {
    int col = cb + wx * 32 + ni * 16 + l16;
    float bc = b2_[col];
#pragma unroll
    for (int reg = 0; reg < 4; ++reg) {
      int row = rb + wy * 16 + quad * 4 + reg;
      float r = xd[(size_t)row * 256 + col] + acc[ni][reg] + bc;
      xd[(size_t)row * 256 + col] = r;
      xb[(size_t)row * 256 + col] = f2b(r);
      if (outp) {
        int ss = row >> 11, bb = (row >> 10) & 1, n = row & 1023;
        outp[(size_t)((bb * 2 + ss) * 1024 + n) * 256 + col] = r;
      }
    }
  }
#undef W2_A_LOAD
#undef W2_A_WRITE
#undef W2_STAGE_B
}

extern "C" void kernel_launch(void* const* d_in, const int* in_sizes, int n_in,
                              void* d_out, int out_size, void* d_ws, size_t ws_size,
                              hipStream_t stream) {
  (void)in_sizes; (void)n_in; (void)out_size; (void)ws_size;
  const float* desc = (const float*)d_in[0];
  const int*   mask = (const int*)d_in[1];
  const float* qw = (const float*)d_in[2];
  const float* qb = (const float*)d_in[3];
  const float* kw = (const float*)d_in[4];
  const float* kb = (const float*)d_in[5];
  const float* vw = (const float*)d_in[6];
  const float* vb = (const float*)d_in[7];
  const float* ow = (const float*)d_in[8];
  const float* ob = (const float*)d_in[9];
  const float* w1 = (const float*)d_in[10];
  const float* b1 = (const float*)d_in[11];
  const float* bn_g = (const float*)d_in[12];
  const float* bn_b = (const float*)d_in[13];
  const float* w2 = (const float*)d_in[14];
  const float* b2 = (const float*)d_in[15];
  float* out = (float*)d_out;

  char* base = (char*)d_ws;
  float* xd    = (float*)(base);                  // [0,4) MB
  float* hbuf  = (float*)(base + (4u << 20));     // [4,12) MB
  short* xb    = (short*)(base + (12u << 20));
  short* qb16  = (short*)(base + (14u << 20));
  short* kb16  = (short*)(base + (16u << 20));
  short* vTb   = (short*)(base + (18u << 20));
  short* attnb = (short*)(base + (20u << 20));
  float* psum  = (float*)(base + (22u << 20));    // [18][2][512]
  float* psq   = psum + 18 * 1024;                // [18][2][512]
  float* beff  = psq + 18 * 1024;                 // 18*512 fp32
  short* wbuf  = (short*)(base + (24u << 20));    // 18*655360 shorts = 23.6 MB

  wprep<<<2500, 256, 0, stream>>>(qw, kw, vw, w1, w2, ob, b1,
                                  wbuf, beff, desc, xd, xb, psum);
  wfuse<<<288, 256, 0, stream>>>(ow, w1, wbuf);

  for (int i = 0; i < 18; ++i) {
    int cross = i & 1;
    short* wb = wbuf + (size_t)i * 655360;

    gemm_qkv<<<dim3(128, 6), 256, 0, stream>>>(
        xb, wb, qb + (size_t)i * 256, kb + (size_t)i * 256, vb + (size_t)i * 256,
        qb16, kb16, vTb, cross);
    attn_mfma<<<dim3(32, 16), 256, 0, stream>>>(qb16, kb16, vTb, mask, attnb, cross);
    gemm_w1<<<dim3(128, 4), 256, 0, stream>>>(xb, attnb, wb + 262144,
                                              beff + (size_t)i * 512,
                                              hbuf, psum + (size_t)i * 1024,
                                              psq + (size_t)i * 1024);
    gemm_w2<<<dim3(128, 4), 256, 0, stream>>>(hbuf, wb + 524288,
                                              b2 + (size_t)i * 256,
                                              psum + (size_t)i * 1024,
                                              psq + (size_t)i * 1024,
                                              bn_g + (size_t)i * 512,
                                              bn_b + (size_t)i * 512, xd, xb,
                                              (i == 17) ? out : nullptr);
  }
}

// Round 7
// 933.002 us; speedup vs baseline: 6.0077x; 1.0142x over previous
//
#include <hip/hip_runtime.h>

// B=2, streams=2, N=1024, D=256, H=4, DH=64, L=18
// Row layout: r = s*2048 + b*1024 + n  (M=4096 rows)
// bf16 MFMA 16x16x32: A-frag lane=A[m=lane&15][k=quad*8+j]; B-frag B[k=quad*8+j][n=lane&15]
// C/D: col=lane&15, row=quad*4+reg
// LDS XOR swizzle: 16B chunk c of row r stored at slot (c ^ (r&7)).
// BN stats PER STREAM (2048 rows each), accumulated via global fp32 atomics.
// R6->R7: GEMMs hold FULL K (or half-K) resident in LDS: one bulk stage + one
// vmcnt(0) wait + straight MFMA run. Barriers/block: qkv 8->1, w1 16->3, w2 16->3.
// qkv/w1: 80KB LDS = exactly 2 blocks/CU. w2: 52KB = 3 blocks/CU.
// NOTE (R5 lesson): persistent kernel + homemade grid barrier = ~69us/barrier on
// CDNA4 (acquire-spin thrashes XCD L2s); kernel boundaries are the cheap sync.

typedef __attribute__((ext_vector_type(8))) short bf16x8;
typedef __attribute__((ext_vector_type(4))) short bf16x4;
typedef __attribute__((ext_vector_type(4))) float floatx4;

__device__ __forceinline__ short f2b(float f) {   // fp32 -> bf16 RNE
  unsigned u = __builtin_bit_cast(unsigned, f);
  unsigned r = (u + 0x7FFFu + ((u >> 16) & 1u)) >> 16;
  return (short)r;
}
__device__ __forceinline__ unsigned pack2(float a, float b) {
  return (unsigned)(unsigned short)f2b(a) | ((unsigned)(unsigned short)f2b(b) << 16);
}
// split a,b into bf16-hi pair (packed) and fp32-residual bf16 pair (packed)
__device__ __forceinline__ void split2(float a, float b, unsigned& h, unsigned& l) {
  unsigned short ha = (unsigned short)f2b(a), hb = (unsigned short)f2b(b);
  float fa = __builtin_bit_cast(float, (unsigned)ha << 16);
  float fb = __builtin_bit_cast(float, (unsigned)hb << 16);
  h = (unsigned)ha | ((unsigned)hb << 16);
  l = pack2(a - fa, b - fb);
}

__device__ __forceinline__ void gl2lds16(const void* g, void* l) {
  __builtin_amdgcn_global_load_lds(
      (const __attribute__((address_space(1))) unsigned*)g,
      (__attribute__((address_space(3))) unsigned*)l, 16, 0, 0);
}

__device__ __forceinline__ floatx4 mfma16_bf16(bf16x4 a, bf16x4 b, floatx4 c) {
#if __has_builtin(__builtin_amdgcn_mfma_f32_16x16x16_bf16)
  return __builtin_amdgcn_mfma_f32_16x16x16_bf16(a, b, c, 0, 0, 0);
#elif __has_builtin(__builtin_amdgcn_mfma_f32_16x16x16bf16_1k)
  return __builtin_amdgcn_mfma_f32_16x16x16bf16_1k(a, b, c, 0, 0, 0);
#else
  asm volatile("v_mfma_f32_16x16x16_bf16 %0, %1, %2, %0" : "+v"(c) : "v"(a), "v"(b));
  return c;
#endif
}

#define BARW   asm volatile("s_barrier" ::: "memory")
#define WAITV8 asm volatile("s_waitcnt vmcnt(8)" ::: "memory")
#define WAITV0 asm volatile("s_waitcnt vmcnt(0)" ::: "memory")
#define LGKM0  asm volatile("s_waitcnt lgkmcnt(0)" ::: "memory")
#define PRIO1  __builtin_amdgcn_s_setprio(1)
#define PRIO0  __builtin_amdgcn_s_setprio(0)

#define GEMM_IDS                                        \
  const int tid = threadIdx.x;                          \
  const int lane = tid & 63, w = tid >> 6;              \
  const int wy = w >> 1, wx = w & 1;                    \
  const int quad = lane >> 4, l16 = lane & 15;          \
  const int lr = lane >> 3;                             \
  const int lcs = (((lane & 7) ^ lr) & 7) * 8;          \
  const floatx4 z4 = {0.f, 0.f, 0.f, 0.f};

// swizzled MFMA K-step (BM=64, BN=128, wave-tile 32x64) -- used by wfuse only
__device__ __forceinline__ void mfma_step_sw(const short* As, const short* Bs,
                                             int wy, int wx, int quad, int l16,
                                             floatx4 acc[2][4]) {
#pragma unroll
  for (int kk = 0; kk < 2; ++kk) {
    const int sw = (((kk * 4 + quad) ^ (l16 & 7)) * 8);
    bf16x8 a0 = *(const bf16x8*)&As[(wy * 32 + l16) * 64 + sw];
    bf16x8 a1 = *(const bf16x8*)&As[(wy * 32 + 16 + l16) * 64 + sw];
    bf16x8 b[4];
#pragma unroll
    for (int ni = 0; ni < 4; ++ni)
      b[ni] = *(const bf16x8*)&Bs[(wx * 64 + ni * 16 + l16) * 64 + sw];
#pragma unroll
    for (int ni = 0; ni < 4; ++ni) {
      acc[0][ni] = __builtin_amdgcn_mfma_f32_16x16x32_bf16(a0, b[ni], acc[0][ni], 0, 0, 0);
      acc[1][ni] = __builtin_amdgcn_mfma_f32_16x16x32_bf16(a1, b[ni], acc[1][ni], 0, 0, 0);
    }
  }
}

// swizzled MFMA K-step (BM=32, BN=128, wave-tile 16x64)
__device__ __forceinline__ void mfma_step_sw32(const short* As, const short* Bs,
                                               int wy, int wx, int quad, int l16,
                                               floatx4 acc[4]) {
#pragma unroll
  for (int kk = 0; kk < 2; ++kk) {
    const int sw = (((kk * 4 + quad) ^ (l16 & 7)) * 8);
    bf16x8 a0 = *(const bf16x8*)&As[(wy * 16 + l16) * 64 + sw];
    bf16x8 b[4];
#pragma unroll
    for (int ni = 0; ni < 4; ++ni)
      b[ni] = *(const bf16x8*)&Bs[(wx * 64 + ni * 16 + l16) * 64 + sw];
#pragma unroll
    for (int ni = 0; ni < 4; ++ni)
      acc[ni] = __builtin_amdgcn_mfma_f32_16x16x32_bf16(a0, b[ni], acc[ni], 0, 0, 0);
  }
}

// swizzled MFMA K-step (BM=32, BN=64, wave-tile 16x32)
__device__ __forceinline__ void mfma_step_sw32x64(const short* As, const short* Bs,
                                                  int wy, int wx, int quad, int l16,
                                                  floatx4 acc[2]) {
#pragma unroll
  for (int kk = 0; kk < 2; ++kk) {
    const int sw = (((kk * 4 + quad) ^ (l16 & 7)) * 8);
    bf16x8 a0 = *(const bf16x8*)&As[(wy * 16 + l16) * 64 + sw];
    bf16x8 b[2];
#pragma unroll
    for (int ni = 0; ni < 2; ++ni)
      b[ni] = *(const bf16x8*)&Bs[(wx * 32 + ni * 16 + l16) * 64 + sw];
#pragma unroll
    for (int ni = 0; ni < 2; ++ni)
      acc[ni] = __builtin_amdgcn_mfma_f32_16x16x32_bf16(a0, b[ni], acc[ni], 0, 0, 0);
  }
}

// ---------- wfuse: F = ow(256x256) @ w1bot(256x512), F^T -> w1t[n][256+kp]
// MFMA with bf16 hi/lo 3-term split. 64x128 tiles, grid 18*16=288.
__global__ __launch_bounds__(256) void wfuse(
    const float* __restrict__ ow, const float* __restrict__ w1,
    short* __restrict__ wbuf) {
  __shared__ short As_h[64 * 64], As_l[64 * 64];
  __shared__ short Bs_h[128 * 64], Bs_l[128 * 64];
  const int blk = blockIdx.x;
  const int layer = blk >> 4, sub = blk & 15;
  const int kp0 = (sub & 3) * 64, n0 = (sub >> 2) * 128;
  const float* A = ow + (size_t)layer * 65536;                 // [kp][i], 256-stride
  const float* Bw = w1 + (size_t)layer * 262144 + 256 * 512;   // [i][n], 512-stride
  short* w1t = wbuf + (size_t)layer * 655360 + 262144;
  GEMM_IDS;
  (void)lr; (void)lcs;
  floatx4 acc[2][4] = {{z4, z4, z4, z4}, {z4, z4, z4, z4}};
  const int ar = tid >> 2, aq = tid & 3;
  const int bn = tid & 127, bkh = tid >> 7;

  for (int s = 0; s < 4; ++s) {
    const int k0 = s * 64;
    const float* Ar = &A[(size_t)(kp0 + ar) * 256 + k0 + aq * 16];
    float4 f0 = *(const float4*)&Ar[0];
    float4 f1 = *(const float4*)&Ar[4];
    float4 f2 = *(const float4*)&Ar[8];
    float4 f3 = *(const float4*)&Ar[12];
    float bv[32];
#pragma unroll
    for (int kk2 = 0; kk2 < 32; ++kk2)
      bv[kk2] = Bw[(size_t)(k0 + bkh * 32 + kk2) * 512 + n0 + bn];

    __syncthreads();
    {
      uint4 hi, lo;
      split2(f0.x, f0.y, hi.x, lo.x);
      split2(f0.z, f0.w, hi.y, lo.y);
      split2(f1.x, f1.y, hi.z, lo.z);
      split2(f1.z, f1.w, hi.w, lo.w);
      int sl = ((aq * 2) ^ (ar & 7)) * 8;
      *(uint4*)&As_h[ar * 64 + sl] = hi;
      *(uint4*)&As_l[ar * 64 + sl] = lo;
      split2(f2.x, f2.y, hi.x, lo.x);
      split2(f2.z, f2.w, hi.y, lo.y);
      split2(f3.x, f3.y, hi.z, lo.z);
      split2(f3.z, f3.w, hi.w, lo.w);
      sl = ((aq * 2 + 1) ^ (ar & 7)) * 8;
      *(uint4*)&As_h[ar * 64 + sl] = hi;
      *(uint4*)&As_l[ar * 64 + sl] = lo;
    }
#pragma unroll
    for (int cc = 0; cc < 4; ++cc) {
      uint4 hi, lo;
      split2(bv[cc * 8 + 0], bv[cc * 8 + 1], hi.x, lo.x);
      split2(bv[cc * 8 + 2], bv[cc * 8 + 3], hi.y, lo.y);
      split2(bv[cc * 8 + 4], bv[cc * 8 + 5], hi.z, lo.z);
      split2(bv[cc * 8 + 6], bv[cc * 8 + 7], hi.w, lo.w);
      int sl = ((bkh * 4 + cc) ^ (bn & 7)) * 8;
      *(uint4*)&Bs_h[bn * 64 + sl] = hi;
      *(uint4*)&Bs_l[bn * 64 + sl] = lo;
    }
    __syncthreads();
    mfma_step_sw(As_h, Bs_h, wy, wx, quad, l16, acc);
    mfma_step_sw(As_h, Bs_l, wy, wx, quad, l16, acc);
    mfma_step_sw(As_l, Bs_h, wy, wx, quad, l16, acc);
  }
#pragma unroll
  for (int mi = 0; mi < 2; ++mi)
#pragma unroll
    for (int ni = 0; ni < 4; ++ni) {
      int col = n0 + wx * 64 + ni * 16 + l16;             // n
      int row0 = kp0 + wy * 32 + mi * 16 + quad * 4;      // kp base
      uint2 uu;
      uu.x = pack2(acc[mi][ni][0], acc[mi][ni][1]);
      uu.y = pack2(acc[mi][ni][2], acc[mi][ni][3]);
      *(uint2*)&w1t[(size_t)col * 512 + 256 + row0] = uu;
    }
}

// ---------- prep kernel:
// blocks [0,1296): wconv transpose+convert, 64k x 128n tiles (8 loads in flight)
// blocks [1296,1440): bfuse
// blocks [1440,2464): input swap-copy
// blocks [2464,2500): zero psum/psq
__global__ __launch_bounds__(256) void wprep(
    const float* __restrict__ qw, const float* __restrict__ kw,
    const float* __restrict__ vw, const float* __restrict__ w1,
    const float* __restrict__ w2, const float* __restrict__ ob,
    const float* __restrict__ b1, short* __restrict__ wbuf,
    float* __restrict__ beff, const float* __restrict__ desc,
    float* __restrict__ xd, short* __restrict__ xb,
    float* __restrict__ psz) {
  __shared__ float SH[64 * 130];
  int blk = blockIdx.x;
  int t = threadIdx.x;
  if (blk < 1296) {
    int layer = blk / 72;
    int sub = blk % 72;
    const float* W; int Kd, Nd, k0, n0; size_t ooff;
    if (sub < 24) {
      int wsel = sub / 8; int tt = sub & 7;
      k0 = (tt >> 1) * 64; n0 = (tt & 1) * 128; Kd = 256; Nd = 256;
      W = (wsel == 0 ? qw : wsel == 1 ? kw : vw) + (size_t)layer * 65536;
      ooff = (size_t)wsel * 65536;
    } else if (sub < 56) {
      int tt = sub - 24; k0 = (tt >> 2) * 64; n0 = (tt & 3) * 128;   // top half of w1
      Kd = 512; Nd = 512; W = w1 + (size_t)layer * 262144; ooff = 262144;
    } else {
      int tt = sub - 56; k0 = (tt >> 1) * 64; n0 = (tt & 1) * 128;
      Kd = 512; Nd = 256; W = w2 + (size_t)layer * 131072; ooff = 524288;
    }
    short* out = wbuf + (size_t)layer * 655360 + ooff;
    const int rr = t >> 4;
    const int c4 = (t & 15) * 4;
#pragma unroll
    for (int i = 0; i < 4; ++i)
#pragma unroll
      for (int hf = 0; hf < 2; ++hf) {
        float4 v = *(const float4*)&W[(size_t)(k0 + i * 16 + rr) * Nd + n0 + hf * 64 + c4];
        float* tp = &SH[(i * 16 + rr) * 130 + hf * 64 + c4];
        tp[0] = v.x; tp[1] = v.y; tp[2] = v.z; tp[3] = v.w;
      }
    __syncthreads();
    const int n = t >> 1;
    const int kh = (t & 1) * 32;
    float v[32];
#pragma unroll
    for (int kk = 0; kk < 32; ++kk)
      v[kk] = SH[(kh + kk) * 130 + n];
    unsigned u[16];
#pragma unroll
    for (int j2 = 0; j2 < 16; ++j2) u[j2] = pack2(v[2 * j2], v[2 * j2 + 1]);
    short* op = &out[(size_t)(n0 + n) * Kd + k0 + kh];
#pragma unroll
    for (int q4 = 0; q4 < 4; ++q4) {
      uint4 o; o.x = u[q4 * 4]; o.y = u[q4 * 4 + 1]; o.z = u[q4 * 4 + 2]; o.w = u[q4 * 4 + 3];
      *(uint4*)&op[q4 * 8] = o;
    }
  } else if (blk < 1440) {
    int bb = blk - 1296;
    int layer = bb >> 3;
    int n0 = (bb & 7) * 64;
    const float* obL = ob + (size_t)layer * 256;
    const float* w1L = w1 + (size_t)layer * 262144 + 256 * 512;
    int n = n0 + (t & 63);
    int part = t >> 6;
    float s = 0.f;
    for (int i = part * 64; i < part * 64 + 64; ++i)
      s += obL[i] * w1L[(size_t)i * 512 + n];
    SH[part * 64 + (t & 63)] = s;
    __syncthreads();
    if (t < 64) {
      float tot = SH[t] + SH[64 + t] + SH[128 + t] + SH[192 + t] +
                  b1[(size_t)layer * 512 + n0 + t];
      beff[(size_t)layer * 512 + n0 + t] = tot;
    }
  } else if (blk < 2464) {
    int idx = (blk - 1440) * 256 + t;
    int fi = idx << 2;
    int hi = (fi >> 19) & 1;
    int lo = (fi >> 18) & 1;
    int sj = (fi & ~(3 << 18)) | (lo << 19) | (hi << 18);
    float4 v = *(const float4*)&desc[sj];
    *(float4*)&xd[fi] = v;
    uint2 uu; uu.x = pack2(v.x, v.y); uu.y = pack2(v.z, v.w);
    *(uint2*)&xb[fi] = uu;
  } else {
    int idx = (blk - 2464) * 1024 + t * 4;
    float4 zz = {0.f, 0.f, 0.f, 0.f};
    *(float4*)&psz[idx] = zz;
  }
}

// ---------- fused QKV GEMM: BM=32, grid (128, 6); v-seg writes V^T
// FULL K=256 resident: As[4][2048] + Bs[4][8192] = 80KB -> 2 blocks/CU.
// One bulk stage (20 gl2lds16/wave), one vmcnt(0)+barrier, 32 MFMA straight.
__global__ __launch_bounds__(256, 2) void gemm_qkv(
    const short* __restrict__ xb, const short* __restrict__ wbufL,
    const float* __restrict__ qb_, const float* __restrict__ kb_,
    const float* __restrict__ vb_,
    short* __restrict__ q, short* __restrict__ kout, short* __restrict__ vT,
    int cross) {
  __shared__ short SM[40960];     // 80KB exactly
  short* As = SM;                 // [4][2048]
  short* Bs = SM + 8192;          // [4][8192]
  const int rb = blockIdx.x * 32;
  const int cb = blockIdx.y * 128;
  const int seg = cb >> 8;
  const int cbl = cb & 255;
  int arb = rb;
  if (seg) arb = (rb & 2047) | ((((rb >> 11) ^ cross) & 1) << 11);
  const short* A = xb + (size_t)arb * 256;
  const short* Wt = wbufL + (size_t)seg * 65536 + (size_t)cbl * 256;
  const float* bias = (seg == 0 ? qb_ : seg == 1 ? kb_ : vb_) + cbl;
  GEMM_IDS;
  floatx4 acc[4] = {z4, z4, z4, z4};

#pragma unroll
  for (int s = 0; s < 4; ++s) {
    const int k0 = s * 64;
    gl2lds16(&A[(size_t)(w * 8 + lr) * 256 + k0 + lcs], &As[s * 2048 + (w * 8) * 64]);
#pragma unroll
    for (int i = 0; i < 4; ++i)
      gl2lds16(&Wt[(size_t)(i * 32 + w * 8 + lr) * 256 + k0 + lcs],
               &Bs[s * 8192 + (i * 32 + w * 8) * 64]);
  }
  WAITV0;
  BARW;
#pragma unroll
  for (int s = 0; s < 4; ++s)
    mfma_step_sw32(&As[s * 2048], &Bs[s * 8192], wy, wx, quad, l16, acc);

  if (seg < 2) {
    short* C = (seg == 0 ? q : kout) + (size_t)rb * 256 + cbl;
#pragma unroll
    for (int ni = 0; ni < 4; ++ni) {
      int col = wx * 64 + ni * 16 + l16;
      float bc = bias[col];
#pragma unroll
      for (int reg = 0; reg < 4; ++reg) {
        int row = wy * 16 + quad * 4 + reg;
        C[(size_t)row * 256 + col] = f2b(acc[ni][reg] + bc);
      }
    }
  } else {
    BARW;                              // all LDS reads done; reuse as scratch
    short* T = SM + w * 1536;          // 64 dims x 24 (pad), wave-local
    const int sb = rb >> 10;
    const int hh = (cbl >> 6) + wx;
    const int z = sb * 4 + hh;
#pragma unroll
    for (int ni = 0; ni < 4; ++ni) {
      int col = wx * 64 + ni * 16 + l16;
      float bc = bias[col];
#pragma unroll
      for (int reg = 0; reg < 4; ++reg)
        T[(ni * 16 + l16) * 24 + quad * 4 + reg] = f2b(acc[ni][reg] + bc);
    }
    short* dst = &vT[((size_t)z * 64 + lane) * 1024 + (rb & 1023) + wy * 16];
    *(uint4*)&dst[0] = *(const uint4*)&T[lane * 24 + 0];
    *(uint4*)&dst[8] = *(const uint4*)&T[lane * 24 + 8];
  }
}

// ---------- flash attention, S^T/O^T form, KV-split.
// grid (32,16), 256 thr = 4 waves: (wq = q sub-tile 0/1) x (wv = KV half 0/1).
// Mask pre-staged to LDS (no vmem in compute). Issue-first + vmcnt(8) pipeline.
__global__ __launch_bounds__(256) void attn_mfma(
    const short* __restrict__ q, const short* __restrict__ k,
    const short* __restrict__ vT, const int* __restrict__ mask,
    short* __restrict__ attnb, int cross) {
  __shared__ short Ks[2][2][4096];   // [buf][wv][64 keys x 64 dims]
  __shared__ short Vs[2][2][4096];   // [buf][wv][64 dims x 64 keys]
  __shared__ float Msk[1024];
  const int tid = threadIdx.x;
  const int lane = tid & 63, w = tid >> 6;
  const int wv = w & 1, wq = w >> 1;
  const int quad = lane >> 4, l16 = lane & 15;
  const int lr = lane >> 3;
  const int lcs = (((lane & 7) ^ lr) & 7) * 8;
  const int qt = blockIdx.x;
  const int z = blockIdx.y;
  const int sb = z >> 2, h = z & 3;
  const int s = sb >> 1, b = sb & 1;
  const int rowbase = sb * 1024;
  const int* mp = mask + (b * 2 + (s ^ cross)) * 1024;

  const int qrow = qt * 32 + wq * 16 + l16;      // this lane's query
  bf16x8 qf[2];
#pragma unroll
  for (int kk = 0; kk < 2; ++kk)
    qf[kk] = *(const bf16x8*)&q[(size_t)(rowbase + qrow) * 256 + h * 64 + kk * 32 + quad * 8];

  {  // mask -> LDS bias, once
    int4 mv = *(const int4*)&mp[tid * 4];
    Msk[tid * 4 + 0] = (mv.x == 0) ? -1.0e9f : 0.f;
    Msk[tid * 4 + 1] = (mv.y == 0) ? -1.0e9f : 0.f;
    Msk[tid * 4 + 2] = (mv.z == 0) ? -1.0e9f : 0.f;
    Msk[tid * 4 + 3] = (mv.w == 0) ? -1.0e9f : 0.f;
  }

  const floatx4 z4 = {0.f, 0.f, 0.f, 0.f};
  floatx4 o4[4] = {z4, z4, z4, z4};
  float mrun = -1e30f, lsum = 0.f;

#define ATT_STAGE(t, buf)                                                               \
  {                                                                                     \
    int key0s = wv * 512 + (t) * 64;                                                    \
    _Pragma("unroll") for (int j = 0; j < 4; ++j) {                                     \
      gl2lds16(&k[(size_t)(rowbase + key0s + j * 16 + wq * 8 + lr) * 256 + h * 64 + lcs], \
               &Ks[buf][wv][(j * 16 + wq * 8) * 64]);                                   \
      gl2lds16(&vT[((size_t)z * 64 + j * 16 + wq * 8 + lr) * 1024 + key0s + lcs],       \
               &Vs[buf][wv][(j * 16 + wq * 8) * 64]);                                   \
    }                                                                                   \
  }

  ATT_STAGE(0, 0);
  __syncthreads();     // drains stage(0) + publishes Msk
  for (int t = 0; t < 8; ++t) {
    int buf = t & 1;
    if (t < 7) { ATT_STAGE(t + 1, buf ^ 1); WAITV8; } else { WAITV0; }
    BARW;
    const int key0 = wv * 512 + t * 64;

    // S^T tiles: A=K-frag (m=key), B=Q-frag (n=query)
    floatx4 sA[4] = {z4, z4, z4, z4};
    PRIO1;
#pragma unroll
    for (int kk = 0; kk < 2; ++kk) {
      const int sw = (((kk * 4 + quad) ^ (l16 & 7)) * 8);
#pragma unroll
      for (int mt = 0; mt < 4; ++mt) {
        bf16x8 kf = *(const bf16x8*)&Ks[buf][wv][(mt * 16 + l16) * 64 + sw];
        sA[mt] = __builtin_amdgcn_mfma_f32_16x16x32_bf16(kf, qf[kk], sA[mt], 0, 0, 0);
      }
    }
    PRIO0;
    float scv[4][4];
    float tmax = -1e30f;
#pragma unroll
    for (int mt = 0; mt < 4; ++mt) {
      float4 mk = *(const float4*)&Msk[key0 + mt * 16 + quad * 4];
      scv[mt][0] = sA[mt][0] * 0.125f + mk.x;
      scv[mt][1] = sA[mt][1] * 0.125f + mk.y;
      scv[mt][2] = sA[mt][2] * 0.125f + mk.z;
      scv[mt][3] = sA[mt][3] * 0.125f + mk.w;
#pragma unroll
      for (int reg = 0; reg < 4; ++reg) tmax = fmaxf(tmax, scv[mt][reg]);
    }
    tmax = fmaxf(tmax, __shfl_xor(tmax, 16));
    tmax = fmaxf(tmax, __shfl_xor(tmax, 32));
    float mnew = fmaxf(mrun, tmax);
    float corr = __expf(mrun - mnew);
    mrun = mnew;
    lsum *= corr;
#pragma unroll
    for (int dt = 0; dt < 4; ++dt)
#pragma unroll
      for (int reg = 0; reg < 4; ++reg) o4[dt][reg] *= corr;

    bf16x4 pb[4];
#pragma unroll
    for (int mt = 0; mt < 4; ++mt) {
      float e0 = __expf(scv[mt][0] - mnew);
      float e1 = __expf(scv[mt][1] - mnew);
      float e2 = __expf(scv[mt][2] - mnew);
      float e3 = __expf(scv[mt][3] - mnew);
      lsum += (e0 + e1) + (e2 + e3);
      union { bf16x4 v; uint2 u; } pu;
      pu.u.x = pack2(e0, e1); pu.u.y = pack2(e2, e3);
      pb[mt] = pu.v;
    }
    // O^T += V^T @ P^T  (P^T straight from registers)
    PRIO1;
#pragma unroll
    for (int mt = 0; mt < 4; ++mt) {
      const int c2 = mt * 2 + (quad >> 1);
      const int sub = (quad & 1) * 4;
#pragma unroll
      for (int dt = 0; dt < 4; ++dt) {
        bf16x4 vf = *(const bf16x4*)&Vs[buf][wv][(dt * 16 + l16) * 64 +
                                                 ((c2 ^ (l16 & 7)) * 8) + sub];
        o4[dt] = mfma16_bf16(vf, pb[mt], o4[dt]);
      }
    }
    PRIO0;
    LGKM0;
    BARW;
  }
  lsum += __shfl_xor(lsum, 16);
  lsum += __shfl_xor(lsum, 32);

  // merge the two KV halves via LDS (reuse Ks as fp32 scratch)
  float* MG = (float*)&Ks[0][0][0];
  const int mo = (wq * 64 + lane) * 18;
  if (wv == 1) {
    MG[mo] = mrun;
    MG[mo + 1] = lsum;
#pragma unroll
    for (int dt = 0; dt < 4; ++dt)
#pragma unroll
      for (int reg = 0; reg < 4; ++reg) MG[mo + 2 + dt * 4 + reg] = o4[dt][reg];
  }
  __syncthreads();
  if (wv == 0) {
    float m2 = MG[mo], l2 = MG[mo + 1];
    float mm = fmaxf(mrun, m2);
    float ca = __expf(mrun - mm), cb2 = __expf(m2 - mm);
    float inv = 1.f / (ca * lsum + cb2 * l2);
    short* op = &attnb[(size_t)(rowbase + qrow) * 256 + h * 64 + quad * 4];
#pragma unroll
    for (int dt = 0; dt < 4; ++dt) {
      float v0 = (ca * o4[dt][0] + cb2 * MG[mo + 2 + dt * 4 + 0]) * inv;
      float v1 = (ca * o4[dt][1] + cb2 * MG[mo + 2 + dt * 4 + 1]) * inv;
      float v2 = (ca * o4[dt][2] + cb2 * MG[mo + 2 + dt * 4 + 2]) * inv;
      float v3 = (ca * o4[dt][3] + cb2 * MG[mo + 2 + dt * 4 + 3]) * inv;
      uint2 uu;
      uu.x = pack2(v0, v1);
      uu.y = pack2(v2, v3);
      *(uint2*)&op[dt * 16] = uu;
    }
  }
#undef ATT_STAGE
}

// ---------- W1 GEMM (concat [x | attn]) + BN partial atomics. BM=32, grid (128,4)
// Half-K resident (K=256 per half), single 80KB buffer, 3 barriers total.
// Ps overlays the dead tile buffer after a __syncthreads (80KB is the 2/CU cap).
__global__ __launch_bounds__(256, 2) void gemm_w1(
    const short* __restrict__ xb, const short* __restrict__ attnb,
    const short* __restrict__ w1t, const float* __restrict__ beff,
    float* __restrict__ hbuf, float* __restrict__ psumL, float* __restrict__ psqL) {
  __shared__ short SM[40960];     // 80KB exactly
  short* As = SM;                 // [4][2048]
  short* Bs = SM + 8192;          // [4][8192]
  const int rb = blockIdx.x * 32, cb = blockIdx.y * 128;
  const int str = rb >> 11;      // stream for BN stats
  GEMM_IDS;
  floatx4 acc[4] = {z4, z4, z4, z4};

#pragma unroll
  for (int h = 0; h < 2; ++h) {
    if (h) BARW;                 // all reads of half-0 done before overwrite
    const short* Ap = (h == 0 ? xb : attnb) + (size_t)rb * 256;
#pragma unroll
    for (int st = 0; st < 4; ++st) {
      const int k0 = h * 256 + st * 64;
      gl2lds16(&Ap[(size_t)(w * 8 + lr) * 256 + st * 64 + lcs],
               &As[st * 2048 + (w * 8) * 64]);
#pragma unroll
      for (int i = 0; i < 4; ++i)
        gl2lds16(&w1t[(size_t)(cb + i * 32 + w * 8 + lr) * 512 + k0 + lcs],
                 &Bs[st * 8192 + (i * 32 + w * 8) * 64]);
    }
    WAITV0;
    BARW;
#pragma unroll
    for (int st = 0; st < 4; ++st)
      mfma_step_sw32(&As[st * 2048], &Bs[st * 8192], wy, wx, quad, l16, acc);
  }

  float colsum[4], colsq[4];
#pragma unroll
  for (int ni = 0; ni < 4; ++ni) { colsum[ni] = 0.f; colsq[ni] = 0.f; }
#pragma unroll
  for (int ni = 0; ni < 4; ++ni) {
    int col = wx * 64 + ni * 16 + l16;
    float bc = beff[cb + col];
#pragma unroll
    for (int reg = 0; reg < 4; ++reg) {
      int row = rb + wy * 16 + quad * 4 + reg;
      float val = acc[ni][reg] + bc;
      hbuf[(size_t)row * 512 + cb + col] = val;
      colsum[ni] += val; colsq[ni] += val * val;
    }
  }
#pragma unroll
  for (int ni = 0; ni < 4; ++ni)
#pragma unroll
    for (int d = 16; d < 64; d <<= 1) {
      colsum[ni] += __shfl_xor(colsum[ni], d);
      colsq[ni]  += __shfl_xor(colsq[ni], d);
    }
  __syncthreads();               // tile-buffer reads done; overlay Ps
  float (*Ps)[2][128] = (float(*)[2][128])SM;
  if (quad == 0) {
#pragma unroll
    for (int ni = 0; ni < 4; ++ni) {
      Ps[wy][0][wx * 64 + ni * 16 + l16] = colsum[ni];
      Ps[wy][1][wx * 64 + ni * 16 + l16] = colsq[ni];
    }
  }
  __syncthreads();
  if (tid < 128) {
    atomicAdd(&psumL[str * 512 + cb + tid], Ps[0][0][tid] + Ps[1][0][tid]);
    atomicAdd(&psqL [str * 512 + cb + tid], Ps[0][1][tid] + Ps[1][1][tid]);
  }
}

// ---------- W2: BN finalize + fused BN/ReLU A-staging + residual.
// Half-K resident (48KB tiles + 4KB BN = 52KB -> 3 blocks/CU), 3 barriers.
// B gl2lds issued first so its latency hides under the A load/transform.
__global__ __launch_bounds__(256, 3) void gemm_w2(
    const float* __restrict__ hbuf, const short* __restrict__ w2t,
    const float* __restrict__ b2_, const float* __restrict__ psumL,
    const float* __restrict__ psqL, const float* __restrict__ g,
    const float* __restrict__ be, float* __restrict__ xd, short* __restrict__ xb,
    float* __restrict__ outp) {
  __shared__ short SM[24576];     // As [4][2048] | Bs [4][4096] = 48KB
  __shared__ float s_scale[512], s_shift[512];
  short* As = SM;
  short* Bs = SM + 8192;
  const int rb = blockIdx.x * 32, cb = blockIdx.y * 64;
  const int str = rb >> 11;
  GEMM_IDS;
  floatx4 acc[2] = {z4, z4};
#pragma unroll
  for (int cc = 0; cc < 2; ++cc) {
    int c = tid + cc * 256;
    float sum = psumL[str * 512 + c];
    float sq  = psqL [str * 512 + c];
    float mean = sum * (1.f / 2048.f);
    float var = sq * (1.f / 2048.f) - mean * mean;
    float rstd = rsqrtf(var + 1e-5f);
    float gs = g[c] * rstd;
    s_scale[c] = gs;
    s_shift[c] = be[c] - mean * gs;
  }
  __syncthreads();

  const int p = tid & 7, ar = tid >> 3;   // ar 0..31

#pragma unroll
  for (int h = 0; h < 2; ++h) {
    if (h) BARW;
    // B first: 8 gl2lds16 in flight while A loads/transforms run
#pragma unroll
    for (int st = 0; st < 4; ++st) {
      const int k0 = h * 256 + st * 64;
#pragma unroll
      for (int i = 0; i < 2; ++i)
        gl2lds16(&w2t[(size_t)(cb + i * 32 + w * 8 + lr) * 512 + k0 + lcs],
                 &Bs[st * 4096 + (i * 32 + w * 8) * 64]);
    }
    // A: load hbuf, BN+ReLU, pack, LDS write
#pragma unroll
    for (int st = 0; st < 4; ++st) {
      const int cs = h * 256 + st * 64 + ((p ^ (ar & 7)) * 8);
      float4 h0 = *(const float4*)&hbuf[(size_t)(rb + ar) * 512 + cs];
      float4 h1 = *(const float4*)&hbuf[(size_t)(rb + ar) * 512 + cs + 4];
      float4 sc0 = *(const float4*)&s_scale[cs];
      float4 sc1 = *(const float4*)&s_scale[cs + 4];
      float4 sh0 = *(const float4*)&s_shift[cs];
      float4 sh1 = *(const float4*)&s_shift[cs + 4];
      uint4 pk;
      pk.x = pack2(fmaxf(h0.x * sc0.x + sh0.x, 0.f), fmaxf(h0.y * sc0.y + sh0.y, 0.f));
      pk.y = pack2(fmaxf(h0.z * sc0.z + sh0.z, 0.f), fmaxf(h0.w * sc0.w + sh0.w, 0.f));
      pk.z = pack2(fmaxf(h1.x * sc1.x + sh1.x, 0.f), fmaxf(h1.y * sc1.y + sh1.y, 0.f));
      pk.w = pack2(fmaxf(h1.z * sc1.z + sh1.z, 0.f), fmaxf(h1.w * sc1.w + sh1.w, 0.f));
      *(uint4*)&As[st * 2048 + ar * 64 + p * 8] = pk;
    }
    WAITV0;
    LGKM0;
    BARW;
#pragma unroll
    for (int st = 0; st < 4; ++st)
      mfma_step_sw32x64(&As[st * 2048], &Bs[st * 4096], wy, wx, quad, l16, acc);
  }

#pragma unroll
  for (int ni = 0; ni < 2; ++ni) {
    int col = cb + wx * 32 + ni * 16 + l16;
    float bc = b2_[col];
#pragma unroll
    for (int reg = 0; reg < 4; ++reg) {
      int row = rb + wy * 16 + quad * 4 + reg;
      float r = xd[(size_t)row * 256 + col] + acc[ni][reg] + bc;
      xd[(size_t)row * 256 + col] = r;
      xb[(size_t)row * 256 + col] = f2b(r);
      if (outp) {
        int ss = row >> 11, bb = (row >> 10) & 1, n = row & 1023;
        outp[(size_t)((bb * 2 + ss) * 1024 + n) * 256 + col] = r;
      }
    }
  }
}

extern "C" void kernel_launch(void* const* d_in, const int* in_sizes, int n_in,
                              void* d_out, int out_size, void* d_ws, size_t ws_size,
                              hipStream_t stream) {
  (void)in_sizes; (void)n_in; (void)out_size; (void)ws_size;
  const float* desc = (const float*)d_in[0];
  const int*   mask = (const int*)d_in[1];
  const float* qw = (const float*)d_in[2];
  const float* qb = (const float*)d_in[3];
  const float* kw = (const float*)d_in[4];
  const float* kb = (const float*)d_in[5];
  const float* vw = (const float*)d_in[6];
  const float* vb = (const float*)d_in[7];
  const float* ow = (const float*)d_in[8];
  const float* ob = (const float*)d_in[9];
  const float* w1 = (const float*)d_in[10];
  const float* b1 = (const float*)d_in[11];
  const float* bn_g = (const float*)d_in[12];
  const float* bn_b = (const float*)d_in[13];
  const float* w2 = (const float*)d_in[14];
  const float* b2 = (const float*)d_in[15];
  float* out = (float*)d_out;

  char* base = (char*)d_ws;
  float* xd    = (float*)(base);                  // [0,4) MB
  float* hbuf  = (float*)(base + (4u << 20));     // [4,12) MB
  short* xb    = (short*)(base + (12u << 20));
  short* qb16  = (short*)(base + (14u << 20));
  short* kb16  = (short*)(base + (16u << 20));
  short* vTb   = (short*)(base + (18u << 20));
  short* attnb = (short*)(base + (20u << 20));
  float* psum  = (float*)(base + (22u << 20));    // [18][2][512]
  float* psq   = psum + 18 * 1024;                // [18][2][512]
  float* beff  = psq + 18 * 1024;                 // 18*512 fp32
  short* wbuf  = (short*)(base + (24u << 20));    // 18*655360 shorts = 23.6 MB

  wprep<<<2500, 256, 0, stream>>>(qw, kw, vw, w1, w2, ob, b1,
                                  wbuf, beff, desc, xd, xb, psum);
  wfuse<<<288, 256, 0, stream>>>(ow, w1, wbuf);

  for (int i = 0; i < 18; ++i) {
    int cross = i & 1;
    short* wb = wbuf + (size_t)i * 655360;

    gemm_qkv<<<dim3(128, 6), 256, 0, stream>>>(
        xb, wb, qb + (size_t)i * 256, kb + (size_t)i * 256, vb + (size_t)i * 256,
        qb16, kb16, vTb, cross);
    attn_mfma<<<dim3(32, 16), 256, 0, stream>>>(qb16, kb16, vTb, mask, attnb, cross);
    gemm_w1<<<dim3(128, 4), 256, 0, stream>>>(xb, attnb, wb + 262144,
                                              beff + (size_t)i * 512,
                                              hbuf, psum + (size_t)i * 1024,
                                              psq + (size_t)i * 1024);
    gemm_w2<<<dim3(128, 4), 256, 0, stream>>>(hbuf, wb + 524288,
                                              b2 + (size_t)i * 256,
                                              psum + (size_t)i * 1024,
                                              psq + (size_t)i * 1024,
                                              bn_g + (size_t)i * 512,
                                              bn_b + (size_t)i * 512, xd, xb,
                                              (i == 17) ? out : nullptr);
  }
}

// Round 8
// 923.238 us; speedup vs baseline: 6.0713x; 1.0106x over previous
//
#include <hip/hip_runtime.h>

// B=2, streams=2, N=1024, D=256, H=4, DH=64, L=18
// Row layout: r = s*2048 + b*1024 + n  (M=4096 rows)
// bf16 MFMA 16x16x32: A-frag lane=A[m=lane&15][k=quad*8+j]; B-frag B[k=quad*8+j][n=lane&15]
// C/D: col=lane&15, row=quad*4+reg
// LDS XOR swizzle: 16B chunk c of row r stored at slot (c ^ (r&7)).
// BN stats PER STREAM (2048 rows each), accumulated via global fp32 atomics.
// R7->R8: attn V single-buffered (stage after post-PV barrier) -> 52KB LDS ->
//   3 blocks/CU (was 2). wconv split to 32-row tiles (2592 blocks, 16.6KB LDS).
// NOTE (R5 lesson): persistent kernel + homemade grid barrier = ~69us/barrier on
// CDNA4 (acquire-spin thrashes XCD L2s); kernel boundaries are the cheap sync.

typedef __attribute__((ext_vector_type(8))) short bf16x8;
typedef __attribute__((ext_vector_type(4))) short bf16x4;
typedef __attribute__((ext_vector_type(4))) float floatx4;

__device__ __forceinline__ short f2b(float f) {   // fp32 -> bf16 RNE
  unsigned u = __builtin_bit_cast(unsigned, f);
  unsigned r = (u + 0x7FFFu + ((u >> 16) & 1u)) >> 16;
  return (short)r;
}
__device__ __forceinline__ unsigned pack2(float a, float b) {
  return (unsigned)(unsigned short)f2b(a) | ((unsigned)(unsigned short)f2b(b) << 16);
}
// split a,b into bf16-hi pair (packed) and fp32-residual bf16 pair (packed)
__device__ __forceinline__ void split2(float a, float b, unsigned& h, unsigned& l) {
  unsigned short ha = (unsigned short)f2b(a), hb = (unsigned short)f2b(b);
  float fa = __builtin_bit_cast(float, (unsigned)ha << 16);
  float fb = __builtin_bit_cast(float, (unsigned)hb << 16);
  h = (unsigned)ha | ((unsigned)hb << 16);
  l = pack2(a - fa, b - fb);
}

__device__ __forceinline__ void gl2lds16(const void* g, void* l) {
  __builtin_amdgcn_global_load_lds(
      (const __attribute__((address_space(1))) unsigned*)g,
      (__attribute__((address_space(3))) unsigned*)l, 16, 0, 0);
}

__device__ __forceinline__ floatx4 mfma16_bf16(bf16x4 a, bf16x4 b, floatx4 c) {
#if __has_builtin(__builtin_amdgcn_mfma_f32_16x16x16_bf16)
  return __builtin_amdgcn_mfma_f32_16x16x16_bf16(a, b, c, 0, 0, 0);
#elif __has_builtin(__builtin_amdgcn_mfma_f32_16x16x16bf16_1k)
  return __builtin_amdgcn_mfma_f32_16x16x16bf16_1k(a, b, c, 0, 0, 0);
#else
  asm volatile("v_mfma_f32_16x16x16_bf16 %0, %1, %2, %0" : "+v"(c) : "v"(a), "v"(b));
  return c;
#endif
}

#define BARW   asm volatile("s_barrier" ::: "memory")
#define WAITV8 asm volatile("s_waitcnt vmcnt(8)" ::: "memory")
#define WAITV4 asm volatile("s_waitcnt vmcnt(4)" ::: "memory")
#define WAITV0 asm volatile("s_waitcnt vmcnt(0)" ::: "memory")
#define LGKM0  asm volatile("s_waitcnt lgkmcnt(0)" ::: "memory")
#define PRIO1  __builtin_amdgcn_s_setprio(1)
#define PRIO0  __builtin_amdgcn_s_setprio(0)

#define GEMM_IDS                                        \
  const int tid = threadIdx.x;                          \
  const int lane = tid & 63, w = tid >> 6;              \
  const int wy = w >> 1, wx = w & 1;                    \
  const int quad = lane >> 4, l16 = lane & 15;          \
  const int lr = lane >> 3;                             \
  const int lcs = (((lane & 7) ^ lr) & 7) * 8;          \
  const floatx4 z4 = {0.f, 0.f, 0.f, 0.f};

// swizzled MFMA K-step (BM=64, BN=128, wave-tile 32x64) -- used by wfuse only
__device__ __forceinline__ void mfma_step_sw(const short* As, const short* Bs,
                                             int wy, int wx, int quad, int l16,
                                             floatx4 acc[2][4]) {
#pragma unroll
  for (int kk = 0; kk < 2; ++kk) {
    const int sw = (((kk * 4 + quad) ^ (l16 & 7)) * 8);
    bf16x8 a0 = *(const bf16x8*)&As[(wy * 32 + l16) * 64 + sw];
    bf16x8 a1 = *(const bf16x8*)&As[(wy * 32 + 16 + l16) * 64 + sw];
    bf16x8 b[4];
#pragma unroll
    for (int ni = 0; ni < 4; ++ni)
      b[ni] = *(const bf16x8*)&Bs[(wx * 64 + ni * 16 + l16) * 64 + sw];
#pragma unroll
    for (int ni = 0; ni < 4; ++ni) {
      acc[0][ni] = __builtin_amdgcn_mfma_f32_16x16x32_bf16(a0, b[ni], acc[0][ni], 0, 0, 0);
      acc[1][ni] = __builtin_amdgcn_mfma_f32_16x16x32_bf16(a1, b[ni], acc[1][ni], 0, 0, 0);
    }
  }
}

// swizzled MFMA K-step (BM=32, BN=128, wave-tile 16x64)
__device__ __forceinline__ void mfma_step_sw32(const short* As, const short* Bs,
                                               int wy, int wx, int quad, int l16,
                                               floatx4 acc[4]) {
#pragma unroll
  for (int kk = 0; kk < 2; ++kk) {
    const int sw = (((kk * 4 + quad) ^ (l16 & 7)) * 8);
    bf16x8 a0 = *(const bf16x8*)&As[(wy * 16 + l16) * 64 + sw];
    bf16x8 b[4];
#pragma unroll
    for (int ni = 0; ni < 4; ++ni)
      b[ni] = *(const bf16x8*)&Bs[(wx * 64 + ni * 16 + l16) * 64 + sw];
#pragma unroll
    for (int ni = 0; ni < 4; ++ni)
      acc[ni] = __builtin_amdgcn_mfma_f32_16x16x32_bf16(a0, b[ni], acc[ni], 0, 0, 0);
  }
}

// swizzled MFMA K-step (BM=32, BN=64, wave-tile 16x32)
__device__ __forceinline__ void mfma_step_sw32x64(const short* As, const short* Bs,
                                                  int wy, int wx, int quad, int l16,
                                                  floatx4 acc[2]) {
#pragma unroll
  for (int kk = 0; kk < 2; ++kk) {
    const int sw = (((kk * 4 + quad) ^ (l16 & 7)) * 8);
    bf16x8 a0 = *(const bf16x8*)&As[(wy * 16 + l16) * 64 + sw];
    bf16x8 b[2];
#pragma unroll
    for (int ni = 0; ni < 2; ++ni)
      b[ni] = *(const bf16x8*)&Bs[(wx * 32 + ni * 16 + l16) * 64 + sw];
#pragma unroll
    for (int ni = 0; ni < 2; ++ni)
      acc[ni] = __builtin_amdgcn_mfma_f32_16x16x32_bf16(a0, b[ni], acc[ni], 0, 0, 0);
  }
}

// ---------- wfuse: F = ow(256x256) @ w1bot(256x512), F^T -> w1t[n][256+kp]
// MFMA with bf16 hi/lo 3-term split. 64x128 tiles, grid 18*16=288.
__global__ __launch_bounds__(256) void wfuse(
    const float* __restrict__ ow, const float* __restrict__ w1,
    short* __restrict__ wbuf) {
  __shared__ short As_h[64 * 64], As_l[64 * 64];
  __shared__ short Bs_h[128 * 64], Bs_l[128 * 64];
  const int blk = blockIdx.x;
  const int layer = blk >> 4, sub = blk & 15;
  const int kp0 = (sub & 3) * 64, n0 = (sub >> 2) * 128;
  const float* A = ow + (size_t)layer * 65536;                 // [kp][i], 256-stride
  const float* Bw = w1 + (size_t)layer * 262144 + 256 * 512;   // [i][n], 512-stride
  short* w1t = wbuf + (size_t)layer * 655360 + 262144;
  GEMM_IDS;
  (void)lr; (void)lcs;
  floatx4 acc[2][4] = {{z4, z4, z4, z4}, {z4, z4, z4, z4}};
  const int ar = tid >> 2, aq = tid & 3;
  const int bn = tid & 127, bkh = tid >> 7;

  for (int s = 0; s < 4; ++s) {
    const int k0 = s * 64;
    const float* Ar = &A[(size_t)(kp0 + ar) * 256 + k0 + aq * 16];
    float4 f0 = *(const float4*)&Ar[0];
    float4 f1 = *(const float4*)&Ar[4];
    float4 f2 = *(const float4*)&Ar[8];
    float4 f3 = *(const float4*)&Ar[12];
    float bv[32];
#pragma unroll
    for (int kk2 = 0; kk2 < 32; ++kk2)
      bv[kk2] = Bw[(size_t)(k0 + bkh * 32 + kk2) * 512 + n0 + bn];

    __syncthreads();
    {
      uint4 hi, lo;
      split2(f0.x, f0.y, hi.x, lo.x);
      split2(f0.z, f0.w, hi.y, lo.y);
      split2(f1.x, f1.y, hi.z, lo.z);
      split2(f1.z, f1.w, hi.w, lo.w);
      int sl = ((aq * 2) ^ (ar & 7)) * 8;
      *(uint4*)&As_h[ar * 64 + sl] = hi;
      *(uint4*)&As_l[ar * 64 + sl] = lo;
      split2(f2.x, f2.y, hi.x, lo.x);
      split2(f2.z, f2.w, hi.y, lo.y);
      split2(f3.x, f3.y, hi.z, lo.z);
      split2(f3.z, f3.w, hi.w, lo.w);
      sl = ((aq * 2 + 1) ^ (ar & 7)) * 8;
      *(uint4*)&As_h[ar * 64 + sl] = hi;
      *(uint4*)&As_l[ar * 64 + sl] = lo;
    }
#pragma unroll
    for (int cc = 0; cc < 4; ++cc) {
      uint4 hi, lo;
      split2(bv[cc * 8 + 0], bv[cc * 8 + 1], hi.x, lo.x);
      split2(bv[cc * 8 + 2], bv[cc * 8 + 3], hi.y, lo.y);
      split2(bv[cc * 8 + 4], bv[cc * 8 + 5], hi.z, lo.z);
      split2(bv[cc * 8 + 6], bv[cc * 8 + 7], hi.w, lo.w);
      int sl = ((bkh * 4 + cc) ^ (bn & 7)) * 8;
      *(uint4*)&Bs_h[bn * 64 + sl] = hi;
      *(uint4*)&Bs_l[bn * 64 + sl] = lo;
    }
    __syncthreads();
    mfma_step_sw(As_h, Bs_h, wy, wx, quad, l16, acc);
    mfma_step_sw(As_h, Bs_l, wy, wx, quad, l16, acc);
    mfma_step_sw(As_l, Bs_h, wy, wx, quad, l16, acc);
  }
#pragma unroll
  for (int mi = 0; mi < 2; ++mi)
#pragma unroll
    for (int ni = 0; ni < 4; ++ni) {
      int col = n0 + wx * 64 + ni * 16 + l16;             // n
      int row0 = kp0 + wy * 32 + mi * 16 + quad * 4;      // kp base
      uint2 uu;
      uu.x = pack2(acc[mi][ni][0], acc[mi][ni][1]);
      uu.y = pack2(acc[mi][ni][2], acc[mi][ni][3]);
      *(uint2*)&w1t[(size_t)col * 512 + 256 + row0] = uu;
    }
}

// ---------- prep kernel:
// blocks [0,2592): wconv transpose+convert, 32k x 128n tiles (16.6KB LDS)
// blocks [2592,2736): bfuse
// blocks [2736,3760): input swap-copy
// blocks [3760,3796): zero psum/psq
__global__ __launch_bounds__(256) void wprep(
    const float* __restrict__ qw, const float* __restrict__ kw,
    const float* __restrict__ vw, const float* __restrict__ w1,
    const float* __restrict__ w2, const float* __restrict__ ob,
    const float* __restrict__ b1, short* __restrict__ wbuf,
    float* __restrict__ beff, const float* __restrict__ desc,
    float* __restrict__ xd, short* __restrict__ xb,
    float* __restrict__ psz) {
  __shared__ float SH[32 * 130];
  int blk = blockIdx.x;
  int t = threadIdx.x;
  if (blk < 2592) {
    int layer = blk / 144;
    int sub2 = blk % 144;
    int sub = sub2 >> 1;          // 0..71, same tile decode as before
    int khalf = sub2 & 1;         // which 32-row half of the 64-row tile
    const float* W; int Kd, Nd, k0, n0; size_t ooff;
    if (sub < 24) {
      int wsel = sub / 8; int tt = sub & 7;
      k0 = (tt >> 1) * 64; n0 = (tt & 1) * 128; Kd = 256; Nd = 256;
      W = (wsel == 0 ? qw : wsel == 1 ? kw : vw) + (size_t)layer * 65536;
      ooff = (size_t)wsel * 65536;
    } else if (sub < 56) {
      int tt = sub - 24; k0 = (tt >> 2) * 64; n0 = (tt & 3) * 128;   // top half of w1
      Kd = 512; Nd = 512; W = w1 + (size_t)layer * 262144; ooff = 262144;
    } else {
      int tt = sub - 56; k0 = (tt >> 1) * 64; n0 = (tt & 1) * 128;
      Kd = 512; Nd = 256; W = w2 + (size_t)layer * 131072; ooff = 524288;
    }
    k0 += khalf * 32;
    short* out = wbuf + (size_t)layer * 655360 + ooff;
    const int rr = t >> 4;          // 0..15
    const int c4 = (t & 15) * 4;
#pragma unroll
    for (int i = 0; i < 2; ++i)
#pragma unroll
      for (int hf = 0; hf < 2; ++hf) {
        float4 v = *(const float4*)&W[(size_t)(k0 + i * 16 + rr) * Nd + n0 + hf * 64 + c4];
        float* tp = &SH[(i * 16 + rr) * 130 + hf * 64 + c4];
        tp[0] = v.x; tp[1] = v.y; tp[2] = v.z; tp[3] = v.w;
      }
    __syncthreads();
    const int n = t >> 1;           // 0..127 col within tile
    const int kh = (t & 1) * 16;    // 16-k half of the 32 rows
    float v[16];
#pragma unroll
    for (int kk = 0; kk < 16; ++kk)
      v[kk] = SH[(kh + kk) * 130 + n];
    unsigned u[8];
#pragma unroll
    for (int j2 = 0; j2 < 8; ++j2) u[j2] = pack2(v[2 * j2], v[2 * j2 + 1]);
    short* op = &out[(size_t)(n0 + n) * Kd + k0 + kh];
    uint4 o1; o1.x = u[0]; o1.y = u[1]; o1.z = u[2]; o1.w = u[3];
    uint4 o2; o2.x = u[4]; o2.y = u[5]; o2.z = u[6]; o2.w = u[7];
    *(uint4*)&op[0] = o1;
    *(uint4*)&op[8] = o2;
  } else if (blk < 2736) {
    int bb = blk - 2592;
    int layer = bb >> 3;
    int n0 = (bb & 7) * 64;
    const float* obL = ob + (size_t)layer * 256;
    const float* w1L = w1 + (size_t)layer * 262144 + 256 * 512;
    int n = n0 + (t & 63);
    int part = t >> 6;
    float s = 0.f;
    for (int i = part * 64; i < part * 64 + 64; ++i)
      s += obL[i] * w1L[(size_t)i * 512 + n];
    SH[part * 64 + (t & 63)] = s;
    __syncthreads();
    if (t < 64) {
      float tot = SH[t] + SH[64 + t] + SH[128 + t] + SH[192 + t] +
                  b1[(size_t)layer * 512 + n0 + t];
      beff[(size_t)layer * 512 + n0 + t] = tot;
    }
  } else if (blk < 3760) {
    int idx = (blk - 2736) * 256 + t;
    int fi = idx << 2;
    int hi = (fi >> 19) & 1;
    int lo = (fi >> 18) & 1;
    int sj = (fi & ~(3 << 18)) | (lo << 19) | (hi << 18);
    float4 v = *(const float4*)&desc[sj];
    *(float4*)&xd[fi] = v;
    uint2 uu; uu.x = pack2(v.x, v.y); uu.y = pack2(v.z, v.w);
    *(uint2*)&xb[fi] = uu;
  } else {
    int idx = (blk - 3760) * 1024 + t * 4;
    float4 zz = {0.f, 0.f, 0.f, 0.f};
    *(float4*)&psz[idx] = zz;
  }
}

// ---------- fused QKV GEMM: BM=32, grid (128, 6); v-seg writes V^T
// FULL K=256 resident: As[4][2048] + Bs[4][8192] = 80KB -> 2 blocks/CU.
__global__ __launch_bounds__(256, 2) void gemm_qkv(
    const short* __restrict__ xb, const short* __restrict__ wbufL,
    const float* __restrict__ qb_, const float* __restrict__ kb_,
    const float* __restrict__ vb_,
    short* __restrict__ q, short* __restrict__ kout, short* __restrict__ vT,
    int cross) {
  __shared__ short SM[40960];     // 80KB exactly
  short* As = SM;                 // [4][2048]
  short* Bs = SM + 8192;          // [4][8192]
  const int rb = blockIdx.x * 32;
  const int cb = blockIdx.y * 128;
  const int seg = cb >> 8;
  const int cbl = cb & 255;
  int arb = rb;
  if (seg) arb = (rb & 2047) | ((((rb >> 11) ^ cross) & 1) << 11);
  const short* A = xb + (size_t)arb * 256;
  const short* Wt = wbufL + (size_t)seg * 65536 + (size_t)cbl * 256;
  const float* bias = (seg == 0 ? qb_ : seg == 1 ? kb_ : vb_) + cbl;
  GEMM_IDS;
  floatx4 acc[4] = {z4, z4, z4, z4};

#pragma unroll
  for (int s = 0; s < 4; ++s) {
    const int k0 = s * 64;
    gl2lds16(&A[(size_t)(w * 8 + lr) * 256 + k0 + lcs], &As[s * 2048 + (w * 8) * 64]);
#pragma unroll
    for (int i = 0; i < 4; ++i)
      gl2lds16(&Wt[(size_t)(i * 32 + w * 8 + lr) * 256 + k0 + lcs],
               &Bs[s * 8192 + (i * 32 + w * 8) * 64]);
  }
  WAITV0;
  BARW;
#pragma unroll
  for (int s = 0; s < 4; ++s)
    mfma_step_sw32(&As[s * 2048], &Bs[s * 8192], wy, wx, quad, l16, acc);

  if (seg < 2) {
    short* C = (seg == 0 ? q : kout) + (size_t)rb * 256 + cbl;
#pragma unroll
    for (int ni = 0; ni < 4; ++ni) {
      int col = wx * 64 + ni * 16 + l16;
      float bc = bias[col];
#pragma unroll
      for (int reg = 0; reg < 4; ++reg) {
        int row = wy * 16 + quad * 4 + reg;
        C[(size_t)row * 256 + col] = f2b(acc[ni][reg] + bc);
      }
    }
  } else {
    BARW;                              // all LDS reads done; reuse as scratch
    short* T = SM + w * 1536;          // 64 dims x 24 (pad), wave-local
    const int sb = rb >> 10;
    const int hh = (cbl >> 6) + wx;
    const int z = sb * 4 + hh;
#pragma unroll
    for (int ni = 0; ni < 4; ++ni) {
      int col = wx * 64 + ni * 16 + l16;
      float bc = bias[col];
#pragma unroll
      for (int reg = 0; reg < 4; ++reg)
        T[(ni * 16 + l16) * 24 + quad * 4 + reg] = f2b(acc[ni][reg] + bc);
    }
    short* dst = &vT[((size_t)z * 64 + lane) * 1024 + (rb & 1023) + wy * 16];
    *(uint4*)&dst[0] = *(const uint4*)&T[lane * 24 + 0];
    *(uint4*)&dst[8] = *(const uint4*)&T[lane * 24 + 8];
  }
}

// ---------- flash attention, S^T/O^T form, KV-split.
// grid (32,16), 256 thr = 4 waves: (wq = q sub-tile 0/1) x (wv = KV half 0/1).
// K double-buffered; V SINGLE-buffered (staged after post-PV barrier).
// LDS 52KB -> 3 blocks/CU. vmcnt: K-wait=8, V-wait=4 (V(t) older than K(t+1)).
__global__ __launch_bounds__(256, 3) void attn_mfma(
    const short* __restrict__ q, const short* __restrict__ k,
    const short* __restrict__ vT, const int* __restrict__ mask,
    short* __restrict__ attnb, int cross) {
  __shared__ short Ks[2][2][4096];   // [buf][wv][64 keys x 64 dims]  32KB
  __shared__ short Vs[2][4096];      // [wv][64 dims x 64 keys]       16KB
  __shared__ float Msk[1024];        //                                4KB
  const int tid = threadIdx.x;
  const int lane = tid & 63, w = tid >> 6;
  const int wv = w & 1, wq = w >> 1;
  const int quad = lane >> 4, l16 = lane & 15;
  const int lr = lane >> 3;
  const int lcs = (((lane & 7) ^ lr) & 7) * 8;
  const int qt = blockIdx.x;
  const int z = blockIdx.y;
  const int sb = z >> 2, h = z & 3;
  const int s = sb >> 1, b = sb & 1;
  const int rowbase = sb * 1024;
  const int* mp = mask + (b * 2 + (s ^ cross)) * 1024;

  const int qrow = qt * 32 + wq * 16 + l16;      // this lane's query
  bf16x8 qf[2];
#pragma unroll
  for (int kk = 0; kk < 2; ++kk)
    qf[kk] = *(const bf16x8*)&q[(size_t)(rowbase + qrow) * 256 + h * 64 + kk * 32 + quad * 8];

  {  // mask -> LDS bias, once
    int4 mv = *(const int4*)&mp[tid * 4];
    Msk[tid * 4 + 0] = (mv.x == 0) ? -1.0e9f : 0.f;
    Msk[tid * 4 + 1] = (mv.y == 0) ? -1.0e9f : 0.f;
    Msk[tid * 4 + 2] = (mv.z == 0) ? -1.0e9f : 0.f;
    Msk[tid * 4 + 3] = (mv.w == 0) ? -1.0e9f : 0.f;
  }

  const floatx4 z4 = {0.f, 0.f, 0.f, 0.f};
  floatx4 o4[4] = {z4, z4, z4, z4};
  float mrun = -1e30f, lsum = 0.f;

#define ATT_STAGE_K(t, buf)                                                             \
  {                                                                                     \
    int key0s = wv * 512 + (t) * 64;                                                    \
    _Pragma("unroll") for (int j = 0; j < 4; ++j)                                       \
      gl2lds16(&k[(size_t)(rowbase + key0s + j * 16 + wq * 8 + lr) * 256 + h * 64 + lcs], \
               &Ks[buf][wv][(j * 16 + wq * 8) * 64]);                                   \
  }
#define ATT_STAGE_V(t)                                                                  \
  {                                                                                     \
    int key0s = wv * 512 + (t) * 64;                                                    \
    _Pragma("unroll") for (int j = 0; j < 4; ++j)                                       \
      gl2lds16(&vT[((size_t)z * 64 + j * 16 + wq * 8 + lr) * 1024 + key0s + lcs],       \
               &Vs[wv][(j * 16 + wq * 8) * 64]);                                        \
  }

  ATT_STAGE_K(0, 0);
  ATT_STAGE_V(0);
  __syncthreads();     // drains all prologue stages + publishes Msk
  for (int t = 0; t < 8; ++t) {
    int buf = t & 1;
    // issue next K; wait own K(t) parts (8 younger allowed: V(t)+K(t+1))
    if (t < 7) { ATT_STAGE_K(t + 1, buf ^ 1); WAITV8; } else { WAITV4; }
    BARW;                                // K(t) visible block-wide
    const int key0 = wv * 512 + t * 64;

    // S^T tiles: A=K-frag (m=key), B=Q-frag (n=query)
    floatx4 sA[4] = {z4, z4, z4, z4};
    PRIO1;
#pragma unroll
    for (int kk = 0; kk < 2; ++kk) {
      const int sw = (((kk * 4 + quad) ^ (l16 & 7)) * 8);
#pragma unroll
      for (int mt = 0; mt < 4; ++mt) {
        bf16x8 kf = *(const bf16x8*)&Ks[buf][wv][(mt * 16 + l16) * 64 + sw];
        sA[mt] = __builtin_amdgcn_mfma_f32_16x16x32_bf16(kf, qf[kk], sA[mt], 0, 0, 0);
      }
    }
    PRIO0;
    float scv[4][4];
    float tmax = -1e30f;
#pragma unroll
    for (int mt = 0; mt < 4; ++mt) {
      float4 mk = *(const float4*)&Msk[key0 + mt * 16 + quad * 4];
      scv[mt][0] = sA[mt][0] * 0.125f + mk.x;
      scv[mt][1] = sA[mt][1] * 0.125f + mk.y;
      scv[mt][2] = sA[mt][2] * 0.125f + mk.z;
      scv[mt][3] = sA[mt][3] * 0.125f + mk.w;
#pragma unroll
      for (int reg = 0; reg < 4; ++reg) tmax = fmaxf(tmax, scv[mt][reg]);
    }
    tmax = fmaxf(tmax, __shfl_xor(tmax, 16));
    tmax = fmaxf(tmax, __shfl_xor(tmax, 32));
    float mnew = fmaxf(mrun, tmax);
    float corr = __expf(mrun - mnew);
    mrun = mnew;
    lsum *= corr;
#pragma unroll
    for (int dt = 0; dt < 4; ++dt)
#pragma unroll
      for (int reg = 0; reg < 4; ++reg) o4[dt][reg] *= corr;

    bf16x4 pb[4];
#pragma unroll
    for (int mt = 0; mt < 4; ++mt) {
      float e0 = __expf(scv[mt][0] - mnew);
      float e1 = __expf(scv[mt][1] - mnew);
      float e2 = __expf(scv[mt][2] - mnew);
      float e3 = __expf(scv[mt][3] - mnew);
      lsum += (e0 + e1) + (e2 + e3);
      union { bf16x4 v; uint2 u; } pu;
      pu.u.x = pack2(e0, e1); pu.u.y = pack2(e2, e3);
      pb[mt] = pu.v;
    }
    // V(t) ready: own parts via vmcnt, cross-wave via barrier
    if (t < 7) { WAITV4; } else { WAITV0; }
    BARW;
    // O^T += V^T @ P^T  (P^T straight from registers)
    PRIO1;
#pragma unroll
    for (int mt = 0; mt < 4; ++mt) {
      const int c2 = mt * 2 + (quad >> 1);
      const int sub = (quad & 1) * 4;
#pragma unroll
      for (int dt = 0; dt < 4; ++dt) {
        bf16x4 vf = *(const bf16x4*)&Vs[wv][(dt * 16 + l16) * 64 +
                                            ((c2 ^ (l16 & 7)) * 8) + sub];
        o4[dt] = mfma16_bf16(vf, pb[mt], o4[dt]);
      }
    }
    PRIO0;
    LGKM0;
    BARW;                 // all PV reads of Vs done -> safe to overwrite
    if (t < 7) ATT_STAGE_V(t + 1);
  }
  lsum += __shfl_xor(lsum, 16);
  lsum += __shfl_xor(lsum, 32);

  // merge the two KV halves via LDS (reuse Ks as fp32 scratch)
  float* MG = (float*)&Ks[0][0][0];
  const int mo = (wq * 64 + lane) * 18;
  if (wv == 1) {
    MG[mo] = mrun;
    MG[mo + 1] = lsum;
#pragma unroll
    for (int dt = 0; dt < 4; ++dt)
#pragma unroll
      for (int reg = 0; reg < 4; ++reg) MG[mo + 2 + dt * 4 + reg] = o4[dt][reg];
  }
  __syncthreads();
  if (wv == 0) {
    float m2 = MG[mo], l2 = MG[mo + 1];
    float mm = fmaxf(mrun, m2);
    float ca = __expf(mrun - mm), cb2 = __expf(m2 - mm);
    float inv = 1.f / (ca * lsum + cb2 * l2);
    short* op = &attnb[(size_t)(rowbase + qrow) * 256 + h * 64 + quad * 4];
#pragma unroll
    for (int dt = 0; dt < 4; ++dt) {
      float v0 = (ca * o4[dt][0] + cb2 * MG[mo + 2 + dt * 4 + 0]) * inv;
      float v1 = (ca * o4[dt][1] + cb2 * MG[mo + 2 + dt * 4 + 1]) * inv;
      float v2 = (ca * o4[dt][2] + cb2 * MG[mo + 2 + dt * 4 + 2]) * inv;
      float v3 = (ca * o4[dt][3] + cb2 * MG[mo + 2 + dt * 4 + 3]) * inv;
      uint2 uu;
      uu.x = pack2(v0, v1);
      uu.y = pack2(v2, v3);
      *(uint2*)&op[dt * 16] = uu;
    }
  }
#undef ATT_STAGE_K
#undef ATT_STAGE_V
}

// ---------- W1 GEMM (concat [x | attn]) + BN partial atomics. BM=32, grid (128,4)
// Half-K resident (K=256 per half), single 80KB buffer, 3 barriers total.
__global__ __launch_bounds__(256, 2) void gemm_w1(
    const short* __restrict__ xb, const short* __restrict__ attnb,
    const short* __restrict__ w1t, const float* __restrict__ beff,
    float* __restrict__ hbuf, float* __restrict__ psumL, float* __restrict__ psqL) {
  __shared__ short SM[40960];     // 80KB exactly
  short* As = SM;                 // [4][2048]
  short* Bs = SM + 8192;          // [4][8192]
  const int rb = blockIdx.x * 32, cb = blockIdx.y * 128;
  const int str = rb >> 11;      // stream for BN stats
  GEMM_IDS;
  floatx4 acc[4] = {z4, z4, z4, z4};

#pragma unroll
  for (int h = 0; h < 2; ++h) {
    if (h) BARW;                 // all reads of half-0 done before overwrite
    const short* Ap = (h == 0 ? xb : attnb) + (size_t)rb * 256;
#pragma unroll
    for (int st = 0; st < 4; ++st) {
      const int k0 = h * 256 + st * 64;
      gl2lds16(&Ap[(size_t)(w * 8 + lr) * 256 + st * 64 + lcs],
               &As[st * 2048 + (w * 8) * 64]);
#pragma unroll
      for (int i = 0; i < 4; ++i)
        gl2lds16(&w1t[(size_t)(cb + i * 32 + w * 8 + lr) * 512 + k0 + lcs],
                 &Bs[st * 8192 + (i * 32 + w * 8) * 64]);
    }
    WAITV0;
    BARW;
#pragma unroll
    for (int st = 0; st < 4; ++st)
      mfma_step_sw32(&As[st * 2048], &Bs[st * 8192], wy, wx, quad, l16, acc);
  }

  float colsum[4], colsq[4];
#pragma unroll
  for (int ni = 0; ni < 4; ++ni) { colsum[ni] = 0.f; colsq[ni] = 0.f; }
#pragma unroll
  for (int ni = 0; ni < 4; ++ni) {
    int col = wx * 64 + ni * 16 + l16;
    float bc = beff[cb + col];
#pragma unroll
    for (int reg = 0; reg < 4; ++reg) {
      int row = rb + wy * 16 + quad * 4 + reg;
      float val = acc[ni][reg] + bc;
      hbuf[(size_t)row * 512 + cb + col] = val;
      colsum[ni] += val; colsq[ni] += val * val;
    }
  }
#pragma unroll
  for (int ni = 0; ni < 4; ++ni)
#pragma unroll
    for (int d = 16; d < 64; d <<= 1) {
      colsum[ni] += __shfl_xor(colsum[ni], d);
      colsq[ni]  += __shfl_xor(colsq[ni], d);
    }
  __syncthreads();               // tile-buffer reads done; overlay Ps
  float (*Ps)[2][128] = (float(*)[2][128])SM;
  if (quad == 0) {
#pragma unroll
    for (int ni = 0; ni < 4; ++ni) {
      Ps[wy][0][wx * 64 + ni * 16 + l16] = colsum[ni];
      Ps[wy][1][wx * 64 + ni * 16 + l16] = colsq[ni];
    }
  }
  __syncthreads();
  if (tid < 128) {
    atomicAdd(&psumL[str * 512 + cb + tid], Ps[0][0][tid] + Ps[1][0][tid]);
    atomicAdd(&psqL [str * 512 + cb + tid], Ps[0][1][tid] + Ps[1][1][tid]);
  }
}

// ---------- W2: BN finalize + fused BN/ReLU A-staging + residual.
// Half-K resident (48KB tiles + 4KB BN = 52KB -> 3 blocks/CU), 3 barriers.
// B gl2lds issued first so its latency hides under the A load/transform.
__global__ __launch_bounds__(256, 3) void gemm_w2(
    const float* __restrict__ hbuf, const short* __restrict__ w2t,
    const float* __restrict__ b2_, const float* __restrict__ psumL,
    const float* __restrict__ psqL, const float* __restrict__ g,
    const float* __restrict__ be, float* __restrict__ xd, short* __restrict__ xb,
    float* __restrict__ outp) {
  __shared__ short SM[24576];     // As [4][2048] | Bs [4][4096] = 48KB
  __shared__ float s_scale[512], s_shift[512];
  short* As = SM;
  short* Bs = SM + 8192;
  const int rb = blockIdx.x * 32, cb = blockIdx.y * 64;
  const int str = rb >> 11;
  GEMM_IDS;
  floatx4 acc[2] = {z4, z4};
#pragma unroll
  for (int cc = 0; cc < 2; ++cc) {
    int c = tid + cc * 256;
    float sum = psumL[str * 512 + c];
    float sq  = psqL [str * 512 + c];
    float mean = sum * (1.f / 2048.f);
    float var = sq * (1.f / 2048.f) - mean * mean;
    float rstd = rsqrtf(var + 1e-5f);
    float gs = g[c] * rstd;
    s_scale[c] = gs;
    s_shift[c] = be[c] - mean * gs;
  }
  __syncthreads();

  const int p = tid & 7, ar = tid >> 3;   // ar 0..31

#pragma unroll
  for (int h = 0; h < 2; ++h) {
    if (h) BARW;
    // B first: 8 gl2lds16 in flight while A loads/transforms run
#pragma unroll
    for (int st = 0; st < 4; ++st) {
      const int k0 = h * 256 + st * 64;
#pragma unroll
      for (int i = 0; i < 2; ++i)
        gl2lds16(&w2t[(size_t)(cb + i * 32 + w * 8 + lr) * 512 + k0 + lcs],
                 &Bs[st * 4096 + (i * 32 + w * 8) * 64]);
    }
    // A: load hbuf, BN+ReLU, pack, LDS write
#pragma unroll
    for (int st = 0; st < 4; ++st) {
      const int cs = h * 256 + st * 64 + ((p ^ (ar & 7)) * 8);
      float4 h0 = *(const float4*)&hbuf[(size_t)(rb + ar) * 512 + cs];
      float4 h1 = *(const float4*)&hbuf[(size_t)(rb + ar) * 512 + cs + 4];
      float4 sc0 = *(const float4*)&s_scale[cs];
      float4 sc1 = *(const float4*)&s_scale[cs + 4];
      float4 sh0 = *(const float4*)&s_shift[cs];
      float4 sh1 = *(const float4*)&s_shift[cs + 4];
      uint4 pk;
      pk.x = pack2(fmaxf(h0.x * sc0.x + sh0.x, 0.f), fmaxf(h0.y * sc0.y + sh0.y, 0.f));
      pk.y = pack2(fmaxf(h0.z * sc0.z + sh0.z, 0.f), fmaxf(h0.w * sc0.w + sh0.w, 0.f));
      pk.z = pack2(fmaxf(h1.x * sc1.x + sh1.x, 0.f), fmaxf(h1.y * sc1.y + sh1.y, 0.f));
      pk.w = pack2(fmaxf(h1.z * sc1.z + sh1.z, 0.f), fmaxf(h1.w * sc1.w + sh1.w, 0.f));
      *(uint4*)&As[st * 2048 + ar * 64 + p * 8] = pk;
    }
    WAITV0;
    LGKM0;
    BARW;
#pragma unroll
    for (int st = 0; st < 4; ++st)
      mfma_step_sw32x64(&As[st * 2048], &Bs[st * 4096], wy, wx, quad, l16, acc);
  }

#pragma unroll
  for (int ni = 0; ni < 2; ++ni) {
    int col = cb + wx * 32 + ni * 16 + l16;
    float bc = b2_[col];
#pragma unroll
    for (int reg = 0; reg < 4; ++reg) {
      int row = rb + wy * 16 + quad * 4 + reg;
      float r = xd[(size_t)row * 256 + col] + acc[ni][reg] + bc;
      xd[(size_t)row * 256 + col] = r;
      xb[(size_t)row * 256 + col] = f2b(r);
      if (outp) {
        int ss = row >> 11, bb = (row >> 10) & 1, n = row & 1023;
        outp[(size_t)((bb * 2 + ss) * 1024 + n) * 256 + col] = r;
      }
    }
  }
}

extern "C" void kernel_launch(void* const* d_in, const int* in_sizes, int n_in,
                              void* d_out, int out_size, void* d_ws, size_t ws_size,
                              hipStream_t stream) {
  (void)in_sizes; (void)n_in; (void)out_size; (void)ws_size;
  const float* desc = (const float*)d_in[0];
  const int*   mask = (const int*)d_in[1];
  const float* qw = (const float*)d_in[2];
  const float* qb = (const float*)d_in[3];
  const float* kw = (const float*)d_in[4];
  const float* kb = (const float*)d_in[5];
  const float* vw = (const float*)d_in[6];
  const float* vb = (const float*)d_in[7];
  const float* ow = (const float*)d_in[8];
  const float* ob = (const float*)d_in[9];
  const float* w1 = (const float*)d_in[10];
  const float* b1 = (const float*)d_in[11];
  const float* bn_g = (const float*)d_in[12];
  const float* bn_b = (const float*)d_in[13];
  const float* w2 = (const float*)d_in[14];
  const float* b2 = (const float*)d_in[15];
  float* out = (float*)d_out;

  char* base = (char*)d_ws;
  float* xd    = (float*)(base);                  // [0,4) MB
  float* hbuf  = (float*)(base + (4u << 20));     // [4,12) MB
  short* xb    = (short*)(base + (12u << 20));
  short* qb16  = (short*)(base + (14u << 20));
  short* kb16  = (short*)(base + (16u << 20));
  short* vTb   = (short*)(base + (18u << 20));
  short* attnb = (short*)(base + (20u << 20));
  float* psum  = (float*)(base + (22u << 20));    // [18][2][512]
  float* psq   = psum + 18 * 1024;                // [18][2][512]
  float* beff  = psq + 18 * 1024;                 // 18*512 fp32
  short* wbuf  = (short*)(base + (24u << 20));    // 18*655360 shorts = 23.6 MB

  wprep<<<3796, 256, 0, stream>>>(qw, kw, vw, w1, w2, ob, b1,
                                  wbuf, beff, desc, xd, xb, psum);
  wfuse<<<288, 256, 0, stream>>>(ow, w1, wbuf);

  for (int i = 0; i < 18; ++i) {
    int cross = i & 1;
    short* wb = wbuf + (size_t)i * 655360;

    gemm_qkv<<<dim3(128, 6), 256, 0, stream>>>(
        xb, wb, qb + (size_t)i * 256, kb + (size_t)i * 256, vb + (size_t)i * 256,
        qb16, kb16, vTb, cross);
    attn_mfma<<<dim3(32, 16), 256, 0, stream>>>(qb16, kb16, vTb, mask, attnb, cross);
    gemm_w1<<<dim3(128, 4), 256, 0, stream>>>(xb, attnb, wb + 262144,
                                              beff + (size_t)i * 512,
                                              hbuf, psum + (size_t)i * 1024,
                                              psq + (size_t)i * 1024);
    gemm_w2<<<dim3(128, 4), 256, 0, stream>>>(hbuf, wb + 524288,
                                              b2 + (size_t)i * 256,
                                              psum + (size_t)i * 1024,
                                              psq + (size_t)i * 1024,
                                              bn_g + (size_t)i * 512,
                                              bn_b + (size_t)i * 512, xd, xb,
                                              (i == 17) ? out : nullptr);
  }
}

// Round 9
// 883.111 us; speedup vs baseline: 6.3471x; 1.0454x over previous
//
#include <hip/hip_runtime.h>

// B=2, streams=2, N=1024, D=256, H=4, DH=64, L=18
// Row layout: r = s*2048 + b*1024 + n  (M=4096 rows)
// bf16 MFMA 16x16x32: A-frag lane=A[m=lane&15][k=quad*8+j]; B-frag B[k=quad*8+j][n=lane&15]
// C/D: col=lane&15, row=quad*4+reg
// LDS XOR swizzle: 16B chunk c of row r stored at slot (c ^ (r&7)).
// BN stats PER STREAM (2048 rows each), accumulated via global fp32 atomics.
// R8->R9: XCD-locality swizzle (T1, m157 form) on all loop kernels: 1-D grids,
//   swz = (bid%8)*(nwg/8) + bid/8, tile decoded from swz with cb/qt FAST so all
//   sharers of an A-row-tile / K-V-slice land on ONE XCD's private L2.
// NOTE (R5 lesson): persistent kernel + homemade grid barrier = ~69us/barrier on
// CDNA4; kernel boundaries (~4us) are the cheap sync. Work ~600us, bounds ~270us.

typedef __attribute__((ext_vector_type(8))) short bf16x8;
typedef __attribute__((ext_vector_type(4))) short bf16x4;
typedef __attribute__((ext_vector_type(4))) float floatx4;

__device__ __forceinline__ short f2b(float f) {   // fp32 -> bf16 RNE
  unsigned u = __builtin_bit_cast(unsigned, f);
  unsigned r = (u + 0x7FFFu + ((u >> 16) & 1u)) >> 16;
  return (short)r;
}
__device__ __forceinline__ unsigned pack2(float a, float b) {
  return (unsigned)(unsigned short)f2b(a) | ((unsigned)(unsigned short)f2b(b) << 16);
}
// split a,b into bf16-hi pair (packed) and fp32-residual bf16 pair (packed)
__device__ __forceinline__ void split2(float a, float b, unsigned& h, unsigned& l) {
  unsigned short ha = (unsigned short)f2b(a), hb = (unsigned short)f2b(b);
  float fa = __builtin_bit_cast(float, (unsigned)ha << 16);
  float fb = __builtin_bit_cast(float, (unsigned)hb << 16);
  h = (unsigned)ha | ((unsigned)hb << 16);
  l = pack2(a - fa, b - fb);
}

__device__ __forceinline__ void gl2lds16(const void* g, void* l) {
  __builtin_amdgcn_global_load_lds(
      (const __attribute__((address_space(1))) unsigned*)g,
      (__attribute__((address_space(3))) unsigned*)l, 16, 0, 0);
}

__device__ __forceinline__ floatx4 mfma16_bf16(bf16x4 a, bf16x4 b, floatx4 c) {
#if __has_builtin(__builtin_amdgcn_mfma_f32_16x16x16_bf16)
  return __builtin_amdgcn_mfma_f32_16x16x16_bf16(a, b, c, 0, 0, 0);
#elif __has_builtin(__builtin_amdgcn_mfma_f32_16x16x16bf16_1k)
  return __builtin_amdgcn_mfma_f32_16x16x16bf16_1k(a, b, c, 0, 0, 0);
#else
  asm volatile("v_mfma_f32_16x16x16_bf16 %0, %1, %2, %0" : "+v"(c) : "v"(a), "v"(b));
  return c;
#endif
}

#define BARW   asm volatile("s_barrier" ::: "memory")
#define WAITV8 asm volatile("s_waitcnt vmcnt(8)" ::: "memory")
#define WAITV4 asm volatile("s_waitcnt vmcnt(4)" ::: "memory")
#define WAITV0 asm volatile("s_waitcnt vmcnt(0)" ::: "memory")
#define LGKM0  asm volatile("s_waitcnt lgkmcnt(0)" ::: "memory")
#define PRIO1  __builtin_amdgcn_s_setprio(1)
#define PRIO0  __builtin_amdgcn_s_setprio(0)

#define GEMM_IDS                                        \
  const int tid = threadIdx.x;                          \
  const int lane = tid & 63, w = tid >> 6;              \
  const int wy = w >> 1, wx = w & 1;                    \
  const int quad = lane >> 4, l16 = lane & 15;          \
  const int lr = lane >> 3;                             \
  const int lcs = (((lane & 7) ^ lr) & 7) * 8;          \
  const floatx4 z4 = {0.f, 0.f, 0.f, 0.f};

// swizzled MFMA K-step (BM=64, BN=128, wave-tile 32x64) -- used by wfuse only
__device__ __forceinline__ void mfma_step_sw(const short* As, const short* Bs,
                                             int wy, int wx, int quad, int l16,
                                             floatx4 acc[2][4]) {
#pragma unroll
  for (int kk = 0; kk < 2; ++kk) {
    const int sw = (((kk * 4 + quad) ^ (l16 & 7)) * 8);
    bf16x8 a0 = *(const bf16x8*)&As[(wy * 32 + l16) * 64 + sw];
    bf16x8 a1 = *(const bf16x8*)&As[(wy * 32 + 16 + l16) * 64 + sw];
    bf16x8 b[4];
#pragma unroll
    for (int ni = 0; ni < 4; ++ni)
      b[ni] = *(const bf16x8*)&Bs[(wx * 64 + ni * 16 + l16) * 64 + sw];
#pragma unroll
    for (int ni = 0; ni < 4; ++ni) {
      acc[0][ni] = __builtin_amdgcn_mfma_f32_16x16x32_bf16(a0, b[ni], acc[0][ni], 0, 0, 0);
      acc[1][ni] = __builtin_amdgcn_mfma_f32_16x16x32_bf16(a1, b[ni], acc[1][ni], 0, 0, 0);
    }
  }
}

// swizzled MFMA K-step (BM=32, BN=128, wave-tile 16x64)
__device__ __forceinline__ void mfma_step_sw32(const short* As, const short* Bs,
                                               int wy, int wx, int quad, int l16,
                                               floatx4 acc[4]) {
#pragma unroll
  for (int kk = 0; kk < 2; ++kk) {
    const int sw = (((kk * 4 + quad) ^ (l16 & 7)) * 8);
    bf16x8 a0 = *(const bf16x8*)&As[(wy * 16 + l16) * 64 + sw];
    bf16x8 b[4];
#pragma unroll
    for (int ni = 0; ni < 4; ++ni)
      b[ni] = *(const bf16x8*)&Bs[(wx * 64 + ni * 16 + l16) * 64 + sw];
#pragma unroll
    for (int ni = 0; ni < 4; ++ni)
      acc[ni] = __builtin_amdgcn_mfma_f32_16x16x32_bf16(a0, b[ni], acc[ni], 0, 0, 0);
  }
}

// swizzled MFMA K-step (BM=32, BN=64, wave-tile 16x32)
__device__ __forceinline__ void mfma_step_sw32x64(const short* As, const short* Bs,
                                                  int wy, int wx, int quad, int l16,
                                                  floatx4 acc[2]) {
#pragma unroll
  for (int kk = 0; kk < 2; ++kk) {
    const int sw = (((kk * 4 + quad) ^ (l16 & 7)) * 8);
    bf16x8 a0 = *(const bf16x8*)&As[(wy * 16 + l16) * 64 + sw];
    bf16x8 b[2];
#pragma unroll
    for (int ni = 0; ni < 2; ++ni)
      b[ni] = *(const bf16x8*)&Bs[(wx * 32 + ni * 16 + l16) * 64 + sw];
#pragma unroll
    for (int ni = 0; ni < 2; ++ni)
      acc[ni] = __builtin_amdgcn_mfma_f32_16x16x32_bf16(a0, b[ni], acc[ni], 0, 0, 0);
  }
}

// ---------- wfuse: F = ow(256x256) @ w1bot(256x512), F^T -> w1t[n][256+kp]
// MFMA with bf16 hi/lo 3-term split. 64x128 tiles, grid 18*16=288.
__global__ __launch_bounds__(256) void wfuse(
    const float* __restrict__ ow, const float* __restrict__ w1,
    short* __restrict__ wbuf) {
  __shared__ short As_h[64 * 64], As_l[64 * 64];
  __shared__ short Bs_h[128 * 64], Bs_l[128 * 64];
  const int blk = blockIdx.x;
  const int layer = blk >> 4, sub = blk & 15;
  const int kp0 = (sub & 3) * 64, n0 = (sub >> 2) * 128;
  const float* A = ow + (size_t)layer * 65536;                 // [kp][i], 256-stride
  const float* Bw = w1 + (size_t)layer * 262144 + 256 * 512;   // [i][n], 512-stride
  short* w1t = wbuf + (size_t)layer * 655360 + 262144;
  GEMM_IDS;
  (void)lr; (void)lcs;
  floatx4 acc[2][4] = {{z4, z4, z4, z4}, {z4, z4, z4, z4}};
  const int ar = tid >> 2, aq = tid & 3;
  const int bn = tid & 127, bkh = tid >> 7;

  for (int s = 0; s < 4; ++s) {
    const int k0 = s * 64;
    const float* Ar = &A[(size_t)(kp0 + ar) * 256 + k0 + aq * 16];
    float4 f0 = *(const float4*)&Ar[0];
    float4 f1 = *(const float4*)&Ar[4];
    float4 f2 = *(const float4*)&Ar[8];
    float4 f3 = *(const float4*)&Ar[12];
    float bv[32];
#pragma unroll
    for (int kk2 = 0; kk2 < 32; ++kk2)
      bv[kk2] = Bw[(size_t)(k0 + bkh * 32 + kk2) * 512 + n0 + bn];

    __syncthreads();
    {
      uint4 hi, lo;
      split2(f0.x, f0.y, hi.x, lo.x);
      split2(f0.z, f0.w, hi.y, lo.y);
      split2(f1.x, f1.y, hi.z, lo.z);
      split2(f1.z, f1.w, hi.w, lo.w);
      int sl = ((aq * 2) ^ (ar & 7)) * 8;
      *(uint4*)&As_h[ar * 64 + sl] = hi;
      *(uint4*)&As_l[ar * 64 + sl] = lo;
      split2(f2.x, f2.y, hi.x, lo.x);
      split2(f2.z, f2.w, hi.y, lo.y);
      split2(f3.x, f3.y, hi.z, lo.z);
      split2(f3.z, f3.w, hi.w, lo.w);
      sl = ((aq * 2 + 1) ^ (ar & 7)) * 8;
      *(uint4*)&As_h[ar * 64 + sl] = hi;
      *(uint4*)&As_l[ar * 64 + sl] = lo;
    }
#pragma unroll
    for (int cc = 0; cc < 4; ++cc) {
      uint4 hi, lo;
      split2(bv[cc * 8 + 0], bv[cc * 8 + 1], hi.x, lo.x);
      split2(bv[cc * 8 + 2], bv[cc * 8 + 3], hi.y, lo.y);
      split2(bv[cc * 8 + 4], bv[cc * 8 + 5], hi.z, lo.z);
      split2(bv[cc * 8 + 6], bv[cc * 8 + 7], hi.w, lo.w);
      int sl = ((bkh * 4 + cc) ^ (bn & 7)) * 8;
      *(uint4*)&Bs_h[bn * 64 + sl] = hi;
      *(uint4*)&Bs_l[bn * 64 + sl] = lo;
    }
    __syncthreads();
    mfma_step_sw(As_h, Bs_h, wy, wx, quad, l16, acc);
    mfma_step_sw(As_h, Bs_l, wy, wx, quad, l16, acc);
    mfma_step_sw(As_l, Bs_h, wy, wx, quad, l16, acc);
  }
#pragma unroll
  for (int mi = 0; mi < 2; ++mi)
#pragma unroll
    for (int ni = 0; ni < 4; ++ni) {
      int col = n0 + wx * 64 + ni * 16 + l16;             // n
      int row0 = kp0 + wy * 32 + mi * 16 + quad * 4;      // kp base
      uint2 uu;
      uu.x = pack2(acc[mi][ni][0], acc[mi][ni][1]);
      uu.y = pack2(acc[mi][ni][2], acc[mi][ni][3]);
      *(uint2*)&w1t[(size_t)col * 512 + 256 + row0] = uu;
    }
}

// ---------- prep kernel:
// blocks [0,2592): wconv transpose+convert, 32k x 128n tiles (16.6KB LDS)
// blocks [2592,2736): bfuse
// blocks [2736,3760): input swap-copy
// blocks [3760,3796): zero psum/psq
__global__ __launch_bounds__(256) void wprep(
    const float* __restrict__ qw, const float* __restrict__ kw,
    const float* __restrict__ vw, const float* __restrict__ w1,
    const float* __restrict__ w2, const float* __restrict__ ob,
    const float* __restrict__ b1, short* __restrict__ wbuf,
    float* __restrict__ beff, const float* __restrict__ desc,
    float* __restrict__ xd, short* __restrict__ xb,
    float* __restrict__ psz) {
  __shared__ float SH[32 * 130];
  int blk = blockIdx.x;
  int t = threadIdx.x;
  if (blk < 2592) {
    int layer = blk / 144;
    int sub2 = blk % 144;
    int sub = sub2 >> 1;          // 0..71, same tile decode as before
    int khalf = sub2 & 1;         // which 32-row half of the 64-row tile
    const float* W; int Kd, Nd, k0, n0; size_t ooff;
    if (sub < 24) {
      int wsel = sub / 8; int tt = sub & 7;
      k0 = (tt >> 1) * 64; n0 = (tt & 1) * 128; Kd = 256; Nd = 256;
      W = (wsel == 0 ? qw : wsel == 1 ? kw : vw) + (size_t)layer * 65536;
      ooff = (size_t)wsel * 65536;
    } else if (sub < 56) {
      int tt = sub - 24; k0 = (tt >> 2) * 64; n0 = (tt & 3) * 128;   // top half of w1
      Kd = 512; Nd = 512; W = w1 + (size_t)layer * 262144; ooff = 262144;
    } else {
      int tt = sub - 56; k0 = (tt >> 1) * 64; n0 = (tt & 1) * 128;
      Kd = 512; Nd = 256; W = w2 + (size_t)layer * 131072; ooff = 524288;
    }
    k0 += khalf * 32;
    short* out = wbuf + (size_t)layer * 655360 + ooff;
    const int rr = t >> 4;          // 0..15
    const int c4 = (t & 15) * 4;
#pragma unroll
    for (int i = 0; i < 2; ++i)
#pragma unroll
      for (int hf = 0; hf < 2; ++hf) {
        float4 v = *(const float4*)&W[(size_t)(k0 + i * 16 + rr) * Nd + n0 + hf * 64 + c4];
        float* tp = &SH[(i * 16 + rr) * 130 + hf * 64 + c4];
        tp[0] = v.x; tp[1] = v.y; tp[2] = v.z; tp[3] = v.w;
      }
    __syncthreads();
    const int n = t >> 1;           // 0..127 col within tile
    const int kh = (t & 1) * 16;    // 16-k half of the 32 rows
    float v[16];
#pragma unroll
    for (int kk = 0; kk < 16; ++kk)
      v[kk] = SH[(kh + kk) * 130 + n];
    unsigned u[8];
#pragma unroll
    for (int j2 = 0; j2 < 8; ++j2) u[j2] = pack2(v[2 * j2], v[2 * j2 + 1]);
    short* op = &out[(size_t)(n0 + n) * Kd + k0 + kh];
    uint4 o1; o1.x = u[0]; o1.y = u[1]; o1.z = u[2]; o1.w = u[3];
    uint4 o2; o2.x = u[4]; o2.y = u[5]; o2.z = u[6]; o2.w = u[7];
    *(uint4*)&op[0] = o1;
    *(uint4*)&op[8] = o2;
  } else if (blk < 2736) {
    int bb = blk - 2592;
    int layer = bb >> 3;
    int n0 = (bb & 7) * 64;
    const float* obL = ob + (size_t)layer * 256;
    const float* w1L = w1 + (size_t)layer * 262144 + 256 * 512;
    int n = n0 + (t & 63);
    int part = t >> 6;
    float s = 0.f;
    for (int i = part * 64; i < part * 64 + 64; ++i)
      s += obL[i] * w1L[(size_t)i * 512 + n];
    SH[part * 64 + (t & 63)] = s;
    __syncthreads();
    if (t < 64) {
      float tot = SH[t] + SH[64 + t] + SH[128 + t] + SH[192 + t] +
                  b1[(size_t)layer * 512 + n0 + t];
      beff[(size_t)layer * 512 + n0 + t] = tot;
    }
  } else if (blk < 3760) {
    int idx = (blk - 2736) * 256 + t;
    int fi = idx << 2;
    int hi = (fi >> 19) & 1;
    int lo = (fi >> 18) & 1;
    int sj = (fi & ~(3 << 18)) | (lo << 19) | (hi << 18);
    float4 v = *(const float4*)&desc[sj];
    *(float4*)&xd[fi] = v;
    uint2 uu; uu.x = pack2(v.x, v.y); uu.y = pack2(v.z, v.w);
    *(uint2*)&xb[fi] = uu;
  } else {
    int idx = (blk - 3760) * 1024 + t * 4;
    float4 zz = {0.f, 0.f, 0.f, 0.f};
    *(float4*)&psz[idx] = zz;
  }
}

// ---------- fused QKV GEMM: 1-D grid 768, XCD swizzle, cb-fast tile order.
// FULL K=256 resident: As[4][2048] + Bs[4][8192] = 80KB -> 2 blocks/CU.
__global__ __launch_bounds__(256, 2) void gemm_qkv(
    const short* __restrict__ xb, const short* __restrict__ wbufL,
    const float* __restrict__ qb_, const float* __restrict__ kb_,
    const float* __restrict__ vb_,
    short* __restrict__ q, short* __restrict__ kout, short* __restrict__ vT,
    int cross) {
  __shared__ short SM[40960];     // 80KB exactly
  short* As = SM;                 // [4][2048]
  short* Bs = SM + 8192;          // [4][8192]
  // XCD-locality: tiles with same rb (sharing A rows) contiguous per XCD
  const int bid = blockIdx.x;
  const int swz = (bid & 7) * 96 + (bid >> 3);   // 768/8 = 96
  const int rb = (swz / 6) * 32;
  const int cb = (swz % 6) * 128;
  const int seg = cb >> 8;
  const int cbl = cb & 255;
  int arb = rb;
  if (seg) arb = (rb & 2047) | ((((rb >> 11) ^ cross) & 1) << 11);
  const short* A = xb + (size_t)arb * 256;
  const short* Wt = wbufL + (size_t)seg * 65536 + (size_t)cbl * 256;
  const float* bias = (seg == 0 ? qb_ : seg == 1 ? kb_ : vb_) + cbl;
  GEMM_IDS;
  floatx4 acc[4] = {z4, z4, z4, z4};

#pragma unroll
  for (int s = 0; s < 4; ++s) {
    const int k0 = s * 64;
    gl2lds16(&A[(size_t)(w * 8 + lr) * 256 + k0 + lcs], &As[s * 2048 + (w * 8) * 64]);
#pragma unroll
    for (int i = 0; i < 4; ++i)
      gl2lds16(&Wt[(size_t)(i * 32 + w * 8 + lr) * 256 + k0 + lcs],
               &Bs[s * 8192 + (i * 32 + w * 8) * 64]);
  }
  WAITV0;
  BARW;
#pragma unroll
  for (int s = 0; s < 4; ++s)
    mfma_step_sw32(&As[s * 2048], &Bs[s * 8192], wy, wx, quad, l16, acc);

  if (seg < 2) {
    short* C = (seg == 0 ? q : kout) + (size_t)rb * 256 + cbl;
#pragma unroll
    for (int ni = 0; ni < 4; ++ni) {
      int col = wx * 64 + ni * 16 + l16;
      float bc = bias[col];
#pragma unroll
      for (int reg = 0; reg < 4; ++reg) {
        int row = wy * 16 + quad * 4 + reg;
        C[(size_t)row * 256 + col] = f2b(acc[ni][reg] + bc);
      }
    }
  } else {
    BARW;                              // all LDS reads done; reuse as scratch
    short* T = SM + w * 1536;          // 64 dims x 24 (pad), wave-local
    const int sb = rb >> 10;
    const int hh = (cbl >> 6) + wx;
    const int z = sb * 4 + hh;
#pragma unroll
    for (int ni = 0; ni < 4; ++ni) {
      int col = wx * 64 + ni * 16 + l16;
      float bc = bias[col];
#pragma unroll
      for (int reg = 0; reg < 4; ++reg)
        T[(ni * 16 + l16) * 24 + quad * 4 + reg] = f2b(acc[ni][reg] + bc);
    }
    short* dst = &vT[((size_t)z * 64 + lane) * 1024 + (rb & 1023) + wy * 16];
    *(uint4*)&dst[0] = *(const uint4*)&T[lane * 24 + 0];
    *(uint4*)&dst[8] = *(const uint4*)&T[lane * 24 + 8];
  }
}

// ---------- flash attention, S^T/O^T form, KV-split.
// 1-D grid 512, XCD swizzle, qt-fast: all 32 readers of a z's K/V on one XCD.
// K double-buffered; V SINGLE-buffered. 52KB -> 3 blocks/CU.
__global__ __launch_bounds__(256, 3) void attn_mfma(
    const short* __restrict__ q, const short* __restrict__ k,
    const short* __restrict__ vT, const int* __restrict__ mask,
    short* __restrict__ attnb, int cross) {
  __shared__ short Ks[2][2][4096];   // [buf][wv][64 keys x 64 dims]  32KB
  __shared__ short Vs[2][4096];      // [wv][64 dims x 64 keys]       16KB
  __shared__ float Msk[1024];        //                                4KB
  const int tid = threadIdx.x;
  const int lane = tid & 63, w = tid >> 6;
  const int wv = w & 1, wq = w >> 1;
  const int quad = lane >> 4, l16 = lane & 15;
  const int lr = lane >> 3;
  const int lcs = (((lane & 7) ^ lr) & 7) * 8;
  const int bid = blockIdx.x;
  const int swz = (bid & 7) * 64 + (bid >> 3);   // 512/8 = 64
  const int qt = swz & 31;
  const int z = swz >> 5;
  const int sb = z >> 2, h = z & 3;
  const int s = sb >> 1, b = sb & 1;
  const int rowbase = sb * 1024;
  const int* mp = mask + (b * 2 + (s ^ cross)) * 1024;

  const int qrow = qt * 32 + wq * 16 + l16;      // this lane's query
  bf16x8 qf[2];
#pragma unroll
  for (int kk = 0; kk < 2; ++kk)
    qf[kk] = *(const bf16x8*)&q[(size_t)(rowbase + qrow) * 256 + h * 64 + kk * 32 + quad * 8];

  {  // mask -> LDS bias, once
    int4 mv = *(const int4*)&mp[tid * 4];
    Msk[tid * 4 + 0] = (mv.x == 0) ? -1.0e9f : 0.f;
    Msk[tid * 4 + 1] = (mv.y == 0) ? -1.0e9f : 0.f;
    Msk[tid * 4 + 2] = (mv.z == 0) ? -1.0e9f : 0.f;
    Msk[tid * 4 + 3] = (mv.w == 0) ? -1.0e9f : 0.f;
  }

  const floatx4 z4 = {0.f, 0.f, 0.f, 0.f};
  floatx4 o4[4] = {z4, z4, z4, z4};
  float mrun = -1e30f, lsum = 0.f;

#define ATT_STAGE_K(t, buf)                                                             \
  {                                                                                     \
    int key0s = wv * 512 + (t) * 64;                                                    \
    _Pragma("unroll") for (int j = 0; j < 4; ++j)                                       \
      gl2lds16(&k[(size_t)(rowbase + key0s + j * 16 + wq * 8 + lr) * 256 + h * 64 + lcs], \
               &Ks[buf][wv][(j * 16 + wq * 8) * 64]);                                   \
  }
#define ATT_STAGE_V(t)                                                                  \
  {                                                                                     \
    int key0s = wv * 512 + (t) * 64;                                                    \
    _Pragma("unroll") for (int j = 0; j < 4; ++j)                                       \
      gl2lds16(&vT[((size_t)z * 64 + j * 16 + wq * 8 + lr) * 1024 + key0s + lcs],       \
               &Vs[wv][(j * 16 + wq * 8) * 64]);                                        \
  }

  ATT_STAGE_K(0, 0);
  ATT_STAGE_V(0);
  __syncthreads();     // drains all prologue stages + publishes Msk
  for (int t = 0; t < 8; ++t) {
    int buf = t & 1;
    // issue next K; wait own K(t) parts (8 younger allowed: V(t)+K(t+1))
    if (t < 7) { ATT_STAGE_K(t + 1, buf ^ 1); WAITV8; } else { WAITV4; }
    BARW;                                // K(t) visible block-wide
    const int key0 = wv * 512 + t * 64;

    // S^T tiles: A=K-frag (m=key), B=Q-frag (n=query)
    floatx4 sA[4] = {z4, z4, z4, z4};
    PRIO1;
#pragma unroll
    for (int kk = 0; kk < 2; ++kk) {
      const int sw = (((kk * 4 + quad) ^ (l16 & 7)) * 8);
#pragma unroll
      for (int mt = 0; mt < 4; ++mt) {
        bf16x8 kf = *(const bf16x8*)&Ks[buf][wv][(mt * 16 + l16) * 64 + sw];
        sA[mt] = __builtin_amdgcn_mfma_f32_16x16x32_bf16(kf, qf[kk], sA[mt], 0, 0, 0);
      }
    }
    PRIO0;
    float scv[4][4];
    float tmax = -1e30f;
#pragma unroll
    for (int mt = 0; mt < 4; ++mt) {
      float4 mk = *(const float4*)&Msk[key0 + mt * 16 + quad * 4];
      scv[mt][0] = sA[mt][0] * 0.125f + mk.x;
      scv[mt][1] = sA[mt][1] * 0.125f + mk.y;
      scv[mt][2] = sA[mt][2] * 0.125f + mk.z;
      scv[mt][3] = sA[mt][3] * 0.125f + mk.w;
#pragma unroll
      for (int reg = 0; reg < 4; ++reg) tmax = fmaxf(tmax, scv[mt][reg]);
    }
    tmax = fmaxf(tmax, __shfl_xor(tmax, 16));
    tmax = fmaxf(tmax, __shfl_xor(tmax, 32));
    float mnew = fmaxf(mrun, tmax);
    float corr = __expf(mrun - mnew);
    mrun = mnew;
    lsum *= corr;
#pragma unroll
    for (int dt = 0; dt < 4; ++dt)
#pragma unroll
      for (int reg = 0; reg < 4; ++reg) o4[dt][reg] *= corr;

    bf16x4 pb[4];
#pragma unroll
    for (int mt = 0; mt < 4; ++mt) {
      float e0 = __expf(scv[mt][0] - mnew);
      float e1 = __expf(scv[mt][1] - mnew);
      float e2 = __expf(scv[mt][2] - mnew);
      float e3 = __expf(scv[mt][3] - mnew);
      lsum += (e0 + e1) + (e2 + e3);
      union { bf16x4 v; uint2 u; } pu;
      pu.u.x = pack2(e0, e1); pu.u.y = pack2(e2, e3);
      pb[mt] = pu.v;
    }
    // V(t) ready: own parts via vmcnt, cross-wave via barrier
    if (t < 7) { WAITV4; } else { WAITV0; }
    BARW;
    // O^T += V^T @ P^T  (P^T straight from registers)
    PRIO1;
#pragma unroll
    for (int mt = 0; mt < 4; ++mt) {
      const int c2 = mt * 2 + (quad >> 1);
      const int sub = (quad & 1) * 4;
#pragma unroll
      for (int dt = 0; dt < 4; ++dt) {
        bf16x4 vf = *(const bf16x4*)&Vs[wv][(dt * 16 + l16) * 64 +
                                            ((c2 ^ (l16 & 7)) * 8) + sub];
        o4[dt] = mfma16_bf16(vf, pb[mt], o4[dt]);
      }
    }
    PRIO0;
    LGKM0;
    BARW;                 // all PV reads of Vs done -> safe to overwrite
    if (t < 7) ATT_STAGE_V(t + 1);
  }
  lsum += __shfl_xor(lsum, 16);
  lsum += __shfl_xor(lsum, 32);

  // merge the two KV halves via LDS (reuse Ks as fp32 scratch)
  float* MG = (float*)&Ks[0][0][0];
  const int mo = (wq * 64 + lane) * 18;
  if (wv == 1) {
    MG[mo] = mrun;
    MG[mo + 1] = lsum;
#pragma unroll
    for (int dt = 0; dt < 4; ++dt)
#pragma unroll
      for (int reg = 0; reg < 4; ++reg) MG[mo + 2 + dt * 4 + reg] = o4[dt][reg];
  }
  __syncthreads();
  if (wv == 0) {
    float m2 = MG[mo], l2 = MG[mo + 1];
    float mm = fmaxf(mrun, m2);
    float ca = __expf(mrun - mm), cb2 = __expf(m2 - mm);
    float inv = 1.f / (ca * lsum + cb2 * l2);
    short* op = &attnb[(size_t)(rowbase + qrow) * 256 + h * 64 + quad * 4];
#pragma unroll
    for (int dt = 0; dt < 4; ++dt) {
      float v0 = (ca * o4[dt][0] + cb2 * MG[mo + 2 + dt * 4 + 0]) * inv;
      float v1 = (ca * o4[dt][1] + cb2 * MG[mo + 2 + dt * 4 + 1]) * inv;
      float v2 = (ca * o4[dt][2] + cb2 * MG[mo + 2 + dt * 4 + 2]) * inv;
      float v3 = (ca * o4[dt][3] + cb2 * MG[mo + 2 + dt * 4 + 3]) * inv;
      uint2 uu;
      uu.x = pack2(v0, v1);
      uu.y = pack2(v2, v3);
      *(uint2*)&op[dt * 16] = uu;
    }
  }
#undef ATT_STAGE_K
#undef ATT_STAGE_V
}

// ---------- W1 GEMM (concat [x | attn]) + BN partial atomics.
// 1-D grid 512, XCD swizzle, cb-fast. Half-K resident, 80KB, 3 barriers.
__global__ __launch_bounds__(256, 2) void gemm_w1(
    const short* __restrict__ xb, const short* __restrict__ attnb,
    const short* __restrict__ w1t, const float* __restrict__ beff,
    float* __restrict__ hbuf, float* __restrict__ psumL, float* __restrict__ psqL) {
  __shared__ short SM[40960];     // 80KB exactly
  short* As = SM;                 // [4][2048]
  short* Bs = SM + 8192;          // [4][8192]
  const int bid = blockIdx.x;
  const int swz = (bid & 7) * 64 + (bid >> 3);   // 512/8 = 64
  const int rb = (swz >> 2) * 32, cb = (swz & 3) * 128;
  const int str = rb >> 11;      // stream for BN stats
  GEMM_IDS;
  floatx4 acc[4] = {z4, z4, z4, z4};

#pragma unroll
  for (int h = 0; h < 2; ++h) {
    if (h) BARW;                 // all reads of half-0 done before overwrite
    const short* Ap = (h == 0 ? xb : attnb) + (size_t)rb * 256;
#pragma unroll
    for (int st = 0; st < 4; ++st) {
      const int k0 = h * 256 + st * 64;
      gl2lds16(&Ap[(size_t)(w * 8 + lr) * 256 + st * 64 + lcs],
               &As[st * 2048 + (w * 8) * 64]);
#pragma unroll
      for (int i = 0; i < 4; ++i)
        gl2lds16(&w1t[(size_t)(cb + i * 32 + w * 8 + lr) * 512 + k0 + lcs],
                 &Bs[st * 8192 + (i * 32 + w * 8) * 64]);
    }
    WAITV0;
    BARW;
#pragma unroll
    for (int st = 0; st < 4; ++st)
      mfma_step_sw32(&As[st * 2048], &Bs[st * 8192], wy, wx, quad, l16, acc);
  }

  float colsum[4], colsq[4];
#pragma unroll
  for (int ni = 0; ni < 4; ++ni) { colsum[ni] = 0.f; colsq[ni] = 0.f; }
#pragma unroll
  for (int ni = 0; ni < 4; ++ni) {
    int col = wx * 64 + ni * 16 + l16;
    float bc = beff[cb + col];
#pragma unroll
    for (int reg = 0; reg < 4; ++reg) {
      int row = rb + wy * 16 + quad * 4 + reg;
      float val = acc[ni][reg] + bc;
      hbuf[(size_t)row * 512 + cb + col] = val;
      colsum[ni] += val; colsq[ni] += val * val;
    }
  }
#pragma unroll
  for (int ni = 0; ni < 4; ++ni)
#pragma unroll
    for (int d = 16; d < 64; d <<= 1) {
      colsum[ni] += __shfl_xor(colsum[ni], d);
      colsq[ni]  += __shfl_xor(colsq[ni], d);
    }
  __syncthreads();               // tile-buffer reads done; overlay Ps
  float (*Ps)[2][128] = (float(*)[2][128])SM;
  if (quad == 0) {
#pragma unroll
    for (int ni = 0; ni < 4; ++ni) {
      Ps[wy][0][wx * 64 + ni * 16 + l16] = colsum[ni];
      Ps[wy][1][wx * 64 + ni * 16 + l16] = colsq[ni];
    }
  }
  __syncthreads();
  if (tid < 128) {
    atomicAdd(&psumL[str * 512 + cb + tid], Ps[0][0][tid] + Ps[1][0][tid]);
    atomicAdd(&psqL [str * 512 + cb + tid], Ps[0][1][tid] + Ps[1][1][tid]);
  }
}

// ---------- W2: BN finalize + fused BN/ReLU A-staging + residual.
// 1-D grid 512, XCD swizzle, cb-fast. Half-K resident 52KB -> 3/CU, 3 barriers.
__global__ __launch_bounds__(256, 3) void gemm_w2(
    const float* __restrict__ hbuf, const short* __restrict__ w2t,
    const float* __restrict__ b2_, const float* __restrict__ psumL,
    const float* __restrict__ psqL, const float* __restrict__ g,
    const float* __restrict__ be, float* __restrict__ xd, short* __restrict__ xb,
    float* __restrict__ outp) {
  __shared__ short SM[24576];     // As [4][2048] | Bs [4][4096] = 48KB
  __shared__ float s_scale[512], s_shift[512];
  short* As = SM;
  short* Bs = SM + 8192;
  const int bid = blockIdx.x;
  const int swz = (bid & 7) * 64 + (bid >> 3);   // 512/8 = 64
  const int rb = (swz >> 2) * 32, cb = (swz & 3) * 64;
  const int str = rb >> 11;
  GEMM_IDS;
  floatx4 acc[2] = {z4, z4};
#pragma unroll
  for (int cc = 0; cc < 2; ++cc) {
    int c = tid + cc * 256;
    float sum = psumL[str * 512 + c];
    float sq  = psqL [str * 512 + c];
    float mean = sum * (1.f / 2048.f);
    float var = sq * (1.f / 2048.f) - mean * mean;
    float rstd = rsqrtf(var + 1e-5f);
    float gs = g[c] * rstd;
    s_scale[c] = gs;
    s_shift[c] = be[c] - mean * gs;
  }
  __syncthreads();

  const int p = tid & 7, ar = tid >> 3;   // ar 0..31

#pragma unroll
  for (int h = 0; h < 2; ++h) {
    if (h) BARW;
    // B first: 8 gl2lds16 in flight while A loads/transforms run
#pragma unroll
    for (int st = 0; st < 4; ++st) {
      const int k0 = h * 256 + st * 64;
#pragma unroll
      for (int i = 0; i < 2; ++i)
        gl2lds16(&w2t[(size_t)(cb + i * 32 + w * 8 + lr) * 512 + k0 + lcs],
                 &Bs[st * 4096 + (i * 32 + w * 8) * 64]);
    }
    // A: load hbuf, BN+ReLU, pack, LDS write
#pragma unroll
    for (int st = 0; st < 4; ++st) {
      const int cs = h * 256 + st * 64 + ((p ^ (ar & 7)) * 8);
      float4 h0 = *(const float4*)&hbuf[(size_t)(rb + ar) * 512 + cs];
      float4 h1 = *(const float4*)&hbuf[(size_t)(rb + ar) * 512 + cs + 4];
      float4 sc0 = *(const float4*)&s_scale[cs];
      float4 sc1 = *(const float4*)&s_scale[cs + 4];
      float4 sh0 = *(const float4*)&s_shift[cs];
      float4 sh1 = *(const float4*)&s_shift[cs + 4];
      uint4 pk;
      pk.x = pack2(fmaxf(h0.x * sc0.x + sh0.x, 0.f), fmaxf(h0.y * sc0.y + sh0.y, 0.f));
      pk.y = pack2(fmaxf(h0.z * sc0.z + sh0.z, 0.f), fmaxf(h0.w * sc0.w + sh0.w, 0.f));
      pk.z = pack2(fmaxf(h1.x * sc1.x + sh1.x, 0.f), fmaxf(h1.y * sc1.y + sh1.y, 0.f));
      pk.w = pack2(fmaxf(h1.z * sc1.z + sh1.z, 0.f), fmaxf(h1.w * sc1.w + sh1.w, 0.f));
      *(uint4*)&As[st * 2048 + ar * 64 + p * 8] = pk;
    }
    WAITV0;
    LGKM0;
    BARW;
#pragma unroll
    for (int st = 0; st < 4; ++st)
      mfma_step_sw32x64(&As[st * 2048], &Bs[st * 4096], wy, wx, quad, l16, acc);
  }

#pragma unroll
  for (int ni = 0; ni < 2; ++ni) {
    int col = cb + wx * 32 + ni * 16 + l16;
    float bc = b2_[col];
#pragma unroll
    for (int reg = 0; reg < 4; ++reg) {
      int row = rb + wy * 16 + quad * 4 + reg;
      float r = xd[(size_t)row * 256 + col] + acc[ni][reg] + bc;
      xd[(size_t)row * 256 + col] = r;
      xb[(size_t)row * 256 + col] = f2b(r);
      if (outp) {
        int ss = row >> 11, bb = (row >> 10) & 1, n = row & 1023;
        outp[(size_t)((bb * 2 + ss) * 1024 + n) * 256 + col] = r;
      }
    }
  }
}

extern "C" void kernel_launch(void* const* d_in, const int* in_sizes, int n_in,
                              void* d_out, int out_size, void* d_ws, size_t ws_size,
                              hipStream_t stream) {
  (void)in_sizes; (void)n_in; (void)out_size; (void)ws_size;
  const float* desc = (const float*)d_in[0];
  const int*   mask = (const int*)d_in[1];
  const float* qw = (const float*)d_in[2];
  const float* qb = (const float*)d_in[3];
  const float* kw = (const float*)d_in[4];
  const float* kb = (const float*)d_in[5];
  const float* vw = (const float*)d_in[6];
  const float* vb = (const float*)d_in[7];
  const float* ow = (const float*)d_in[8];
  const float* ob = (const float*)d_in[9];
  const float* w1 = (const float*)d_in[10];
  const float* b1 = (const float*)d_in[11];
  const float* bn_g = (const float*)d_in[12];
  const float* bn_b = (const float*)d_in[13];
  const float* w2 = (const float*)d_in[14];
  const float* b2 = (const float*)d_in[15];
  float* out = (float*)d_out;

  char* base = (char*)d_ws;
  float* xd    = (float*)(base);                  // [0,4) MB
  float* hbuf  = (float*)(base + (4u << 20));     // [4,12) MB
  short* xb    = (short*)(base + (12u << 20));
  short* qb16  = (short*)(base + (14u << 20));
  short* kb16  = (short*)(base + (16u << 20));
  short* vTb   = (short*)(base + (18u << 20));
  short* attnb = (short*)(base + (20u << 20));
  float* psum  = (float*)(base + (22u << 20));    // [18][2][512]
  float* psq   = psum + 18 * 1024;                // [18][2][512]
  float* beff  = psq + 18 * 1024;                 // 18*512 fp32
  short* wbuf  = (short*)(base + (24u << 20));    // 18*655360 shorts = 23.6 MB

  wprep<<<3796, 256, 0, stream>>>(qw, kw, vw, w1, w2, ob, b1,
                                  wbuf, beff, desc, xd, xb, psum);
  wfuse<<<288, 256, 0, stream>>>(ow, w1, wbuf);

  for (int i = 0; i < 18; ++i) {
    int cross = i & 1;
    short* wb = wbuf + (size_t)i * 655360;

    gemm_qkv<<<768, 256, 0, stream>>>(
        xb, wb, qb + (size_t)i * 256, kb + (size_t)i * 256, vb + (size_t)i * 256,
        qb16, kb16, vTb, cross);
    attn_mfma<<<512, 256, 0, stream>>>(qb16, kb16, vTb, mask, attnb, cross);
    gemm_w1<<<512, 256, 0, stream>>>(xb, attnb, wb + 262144,
                                     beff + (size_t)i * 512,
                                     hbuf, psum + (size_t)i * 1024,
                                     psq + (size_t)i * 1024);
    gemm_w2<<<512, 256, 0, stream>>>(hbuf, wb + 524288,
                                     b2 + (size_t)i * 256,
                                     psum + (size_t)i * 1024,
                                     psq + (size_t)i * 1024,
                                     bn_g + (size_t)i * 512,
                                     bn_b + (size_t)i * 512, xd, xb,
                                     (i == 17) ? out : nullptr);
  }
}